// Round 1
// baseline (15115.050 us; speedup 1.0000x reference)
//
#include <hip/hip_runtime.h>

// ---------------------------------------------------------------------------
// SEAL GNN pipeline, fp32.
// Pipeline:
//   deg (node + macro) -> dinv/drecip
//   L1: xw1 = x@W1;       B = xw1*drecip + b1;  B += scatter(xw1[src]*norm)   ; h1 = relu(B) fused into next load
//   L2: xw2 = relu(B)@W2; B = xw2*drecip + b2;  B += scatter(...)             ; h2 = relu(B) fused into pool
//   pool: loc[g] = mean over sorted-batch segment of (relu(B) @ FW1 + Fb1)    (no atomics: binary search)
//   ic  = loc @ FW2 + Fb2
//   macro L1/L2: GCN(128->128) + BN + relu ; glob = z2
//   hc  = GCN(glob, MW3, mb3)  (10 outputs)
// ---------------------------------------------------------------------------

__global__ void count_kernel(const int* __restrict__ dst, float* __restrict__ cnt, int E) {
    int e = blockIdx.x * blockDim.x + threadIdx.x;
    if (e < E) atomicAdd(&cnt[dst[e]], 1.0f);
}

__global__ void finalize_deg(const float* __restrict__ cnt, float* __restrict__ dinv,
                             float* __restrict__ drecip, int n) {
    int i = blockIdx.x * blockDim.x + threadIdx.x;
    if (i < n) {
        float c = cnt[i] + 1.0f;          // self-loop included
        dinv[i]   = rsqrtf(c);
        drecip[i] = 1.0f / c;
    }
}

// XW = (relu?(X)) @ W  [N x 64 @ 64 x 64];  AGG = XW*drecip + bias
// X may alias AGG (per-thread row read-then-write; no cross-thread hazard).
__global__ __launch_bounds__(256) void gemm_n64(const float* X, const float* __restrict__ W,
                                                const float* __restrict__ bias,
                                                const float* __restrict__ drecip,
                                                float* XW, float* AGG, int N, int relu_in) {
    __shared__ float Ws[4096];
    __shared__ float bs[64];
    for (int i = threadIdx.x; i < 4096; i += 256) Ws[i] = W[i];
    if (threadIdx.x < 64) bs[threadIdx.x] = bias[threadIdx.x];
    __syncthreads();
    int i = blockIdx.x * 256 + threadIdx.x;
    if (i >= N) return;
    const float4* xr = (const float4*)(X + (size_t)i * 64);
    float acc[64];
#pragma unroll
    for (int j = 0; j < 64; j++) acc[j] = 0.f;
#pragma unroll
    for (int k4 = 0; k4 < 16; k4++) {
        float4 v = xr[k4];
        if (relu_in) {
            v.x = fmaxf(v.x, 0.f); v.y = fmaxf(v.y, 0.f);
            v.z = fmaxf(v.z, 0.f); v.w = fmaxf(v.w, 0.f);
        }
        float xv[4] = {v.x, v.y, v.z, v.w};
#pragma unroll
        for (int d = 0; d < 4; d++) {
            float xs = xv[d];
            const float* wr = &Ws[(k4 * 4 + d) * 64];
#pragma unroll
            for (int j = 0; j < 64; j++) acc[j] += xs * wr[j];
        }
    }
    float dr = drecip[i];
    float4* xw4 = (float4*)(XW + (size_t)i * 64);
    float4* ag4 = (float4*)(AGG + (size_t)i * 64);
#pragma unroll
    for (int j4 = 0; j4 < 16; j4++) {
        float4 a;
        a.x = acc[4 * j4 + 0]; a.y = acc[4 * j4 + 1];
        a.z = acc[4 * j4 + 2]; a.w = acc[4 * j4 + 3];
        xw4[j4] = a;
        float4 b;
        b.x = a.x * dr + bs[4 * j4 + 0]; b.y = a.y * dr + bs[4 * j4 + 1];
        b.z = a.z * dr + bs[4 * j4 + 2]; b.w = a.w * dr + bs[4 * j4 + 3];
        ag4[j4] = b;
    }
}

// AGG[dst] += XW[src] * dinv[src]*dinv[dst]   (F features, F/4 threads per edge)
template <int F>
__global__ void edge_agg(const int* __restrict__ src, const int* __restrict__ dst,
                         const float* __restrict__ dinv, const float* __restrict__ XW,
                         float* __restrict__ AGG, int E) {
    constexpr int TPE = F / 4;
    int idx = blockIdx.x * blockDim.x + threadIdx.x;
    int e = idx / TPE;
    if (e >= E) return;
    int c = (idx % TPE) * 4;
    int s = src[e], d = dst[e];
    float w = dinv[s] * dinv[d];
    float4 v = *(const float4*)(XW + (size_t)s * F + c);
    float* out = AGG + (size_t)d * F + c;
    atomicAdd(out + 0, v.x * w);
    atomicAdd(out + 1, v.y * w);
    atomicAdd(out + 2, v.z * w);
    atomicAdd(out + 3, v.w * w);
}

// loc[g] = mean over batch-segment of (relu(B) @ FW1 + Fb1). batch sorted -> binary search.
__global__ __launch_bounds__(128) void pool_kernel(const float* __restrict__ B,
                                                   const int* __restrict__ batch,
                                                   const float* __restrict__ FW1,
                                                   const float* __restrict__ Fb1,
                                                   float* __restrict__ loc, int N) {
    int g = blockIdx.x;
    int t = threadIdx.x;
    __shared__ float Ws[64 * 128];
    __shared__ float xs[8][64];
    for (int i = t; i < 64 * 128; i += 128) Ws[i] = FW1[i];
    // lower_bound(batch, g), lower_bound(batch, g+1) -- all threads redundantly
    int lo = 0, hi = N;
    while (lo < hi) { int m = (lo + hi) >> 1; if (batch[m] < g) lo = m + 1; else hi = m; }
    int start = lo;
    hi = N;
    while (lo < hi) { int m = (lo + hi) >> 1; if (batch[m] < g + 1) lo = m + 1; else hi = m; }
    int end = lo;
    __syncthreads();
    float acc = 0.f;
    for (int base = start; base < end; base += 8) {
        int m = min(8, end - base);
        for (int i = t; i < m * 64; i += 128) {
            xs[i >> 6][i & 63] = fmaxf(B[(size_t)(base + (i >> 6)) * 64 + (i & 63)], 0.f);
        }
        __syncthreads();
        for (int r = 0; r < m; r++) {
#pragma unroll
            for (int k = 0; k < 64; k++) acc += xs[r][k] * Ws[k * 128 + t];
        }
        __syncthreads();
    }
    int cnt = end - start;
    acc += (float)cnt * Fb1[t];
    loc[(size_t)g * 128 + t] = acc / fmaxf((float)cnt, 1.f);
}

// ic = loc @ FW2 + Fb2  (G x 128 @ 128 x 10); thread 0 also writes the trailing scalar 0.
__global__ __launch_bounds__(256) void ic_kernel(const float* __restrict__ loc,
                                                 const float* __restrict__ FW2,
                                                 const float* __restrict__ Fb2,
                                                 float* __restrict__ ic,
                                                 float* __restrict__ scalar_out, int G) {
    __shared__ float Ws[1280];
    __shared__ float bs[10];
    for (int i = threadIdx.x; i < 1280; i += 256) Ws[i] = FW2[i];
    if (threadIdx.x < 10) bs[threadIdx.x] = Fb2[threadIdx.x];
    __syncthreads();
    int g = blockIdx.x * 256 + threadIdx.x;
    if (g == 0) scalar_out[0] = 0.f;
    if (g >= G) return;
    float acc[10];
#pragma unroll
    for (int j = 0; j < 10; j++) acc[j] = bs[j];
    const float* xr = loc + (size_t)g * 128;
    for (int k = 0; k < 128; k++) {
        float xv = xr[k];
#pragma unroll
        for (int j = 0; j < 10; j++) acc[j] += xv * Ws[k * 10 + j];
    }
    float* o = ic + (size_t)g * 10;
#pragma unroll
    for (int j = 0; j < 10; j++) o[j] = acc[j];
}

// ZW = X @ W  [G x 128 @ 128 x 128]; AGG = ZW*mdrecip + bias. 2 threads per row.
__global__ __launch_bounds__(256) void gemm_g128(const float* __restrict__ X,
                                                 const float* __restrict__ W,
                                                 const float* __restrict__ bias,
                                                 const float* __restrict__ mdrecip,
                                                 float* __restrict__ ZW,
                                                 float* __restrict__ AGG, int G) {
    __shared__ float Ws[128 * 128];  // 64 KiB
    __shared__ float bs[128];
    for (int i = threadIdx.x; i < 128 * 128; i += 256) Ws[i] = W[i];
    if (threadIdx.x < 128) bs[threadIdx.x] = bias[threadIdx.x];
    __syncthreads();
    int idx = blockIdx.x * 256 + threadIdx.x;
    int g = idx >> 1;
    int half = (idx & 1) * 64;
    if (g >= G) return;
    float acc[64];
#pragma unroll
    for (int j = 0; j < 64; j++) acc[j] = 0.f;
    const float4* xr = (const float4*)(X + (size_t)g * 128);
#pragma unroll 4
    for (int k4 = 0; k4 < 32; k4++) {
        float4 v = xr[k4];
        float xv[4] = {v.x, v.y, v.z, v.w};
#pragma unroll
        for (int d = 0; d < 4; d++) {
            float xs = xv[d];
            const float* wr = &Ws[(k4 * 4 + d) * 128 + half];
#pragma unroll
            for (int j = 0; j < 64; j++) acc[j] += xs * wr[j];
        }
    }
    float dr = mdrecip[g];
    float* zw = ZW + (size_t)g * 128 + half;
    float* ag = AGG + (size_t)g * 128 + half;
#pragma unroll
    for (int j = 0; j < 64; j++) {
        zw[j] = acc[j];
        ag[j] = acc[j] * dr + bs[half + j];
    }
}

// Z = relu(BN(A)) elementwise over G*128
__global__ void bnrelu_kernel(const float* __restrict__ A, const float* __restrict__ gam,
                              const float* __restrict__ bet, const float* __restrict__ mean,
                              const float* __restrict__ var, float* __restrict__ Z, int total) {
    int idx = blockIdx.x * blockDim.x + threadIdx.x;
    if (idx >= total) return;
    int j = idx & 127;
    float v = (A[idx] - mean[j]) * rsqrtf(var[j] + 1e-5f) * gam[j] + bet[j];
    Z[idx] = fmaxf(v, 0.f);
}

// ZW = X @ W [G x 128 @ 128 x 10]; HC = ZW*mdrecip + bias
__global__ __launch_bounds__(256) void gemm_g10(const float* __restrict__ X,
                                                const float* __restrict__ W,
                                                const float* __restrict__ bias,
                                                const float* __restrict__ mdrecip,
                                                float* __restrict__ ZW,
                                                float* __restrict__ HC, int G) {
    __shared__ float Ws[1280];
    __shared__ float bs[10];
    for (int i = threadIdx.x; i < 1280; i += 256) Ws[i] = W[i];
    if (threadIdx.x < 10) bs[threadIdx.x] = bias[threadIdx.x];
    __syncthreads();
    int g = blockIdx.x * 256 + threadIdx.x;
    if (g >= G) return;
    float acc[10];
#pragma unroll
    for (int j = 0; j < 10; j++) acc[j] = 0.f;
    const float4* xr = (const float4*)(X + (size_t)g * 128);
#pragma unroll 4
    for (int k4 = 0; k4 < 32; k4++) {
        float4 v = xr[k4];
        float xv[4] = {v.x, v.y, v.z, v.w};
#pragma unroll
        for (int d = 0; d < 4; d++) {
            float xs = xv[d];
            int k = k4 * 4 + d;
#pragma unroll
            for (int j = 0; j < 10; j++) acc[j] += xs * Ws[k * 10 + j];
        }
    }
    float dr = mdrecip[g];
    float* zw = ZW + (size_t)g * 10;
    float* hc = HC + (size_t)g * 10;
#pragma unroll
    for (int j = 0; j < 10; j++) {
        zw[j] = acc[j];
        hc[j] = acc[j] * dr + bs[j];
    }
}

// HC[md] += ZW[ms] * mdinv[ms]*mdinv[md]  (10 features, 1 thread per edge)
__global__ void edge_agg10(const int* __restrict__ ms, const int* __restrict__ md,
                           const float* __restrict__ mdinv, const float* __restrict__ ZW,
                           float* __restrict__ HC, int EM) {
    int e = blockIdx.x * blockDim.x + threadIdx.x;
    if (e >= EM) return;
    int s = ms[e], d = md[e];
    float w = mdinv[s] * mdinv[d];
    const float* zr = ZW + (size_t)s * 10;
    float* out = HC + (size_t)d * 10;
#pragma unroll
    for (int j = 0; j < 10; j++) atomicAdd(out + j, zr[j] * w);
}

extern "C" void kernel_launch(void* const* d_in, const int* in_sizes, int n_in,
                              void* d_out, int out_size, void* d_ws, size_t ws_size,
                              hipStream_t stream) {
    const float* x    = (const float*)d_in[0];
    const int*   ei   = (const int*)d_in[1];
    const int*   batch= (const int*)d_in[2];
    const int*   me   = (const int*)d_in[3];
    const float* W1   = (const float*)d_in[5];
    const float* b1   = (const float*)d_in[6];
    const float* W2   = (const float*)d_in[7];
    const float* b2   = (const float*)d_in[8];
    const float* FW1  = (const float*)d_in[9];
    const float* Fb1  = (const float*)d_in[10];
    const float* FW2  = (const float*)d_in[11];
    const float* Fb2  = (const float*)d_in[12];
    const float* MW1  = (const float*)d_in[13];
    const float* mb1  = (const float*)d_in[14];
    const float* g1   = (const float*)d_in[15];
    const float* be1  = (const float*)d_in[16];
    const float* m1   = (const float*)d_in[17];
    const float* v1   = (const float*)d_in[18];
    const float* MW2  = (const float*)d_in[19];
    const float* mb2  = (const float*)d_in[20];
    const float* g2   = (const float*)d_in[21];
    const float* be2  = (const float*)d_in[22];
    const float* m2   = (const float*)d_in[23];
    const float* v2   = (const float*)d_in[24];
    const float* MW3  = (const float*)d_in[25];
    const float* mb3  = (const float*)d_in[26];

    const int N  = in_sizes[0] / 64;
    const int E  = in_sizes[1] / 2;
    const int EM = in_sizes[3] / 2;
    const int G  = (out_size - 1) / 276;   // out = G*10 + G*10 + G*128 + G*128 + 1

    float* out    = (float*)d_out;
    float* hc     = out;
    float* ic     = out + (size_t)G * 10;
    float* loc    = out + (size_t)G * 20;
    float* glob   = out + (size_t)G * 20 + (size_t)G * 128;
    float* scalar = out + (size_t)G * 276;

    char*  ws  = (char*)d_ws;
    size_t off = 0;
    auto alloc = [&](size_t bytes) -> float* {
        float* p = (float*)(ws + off);
        off += (bytes + 255) & ~(size_t)255;
        return p;
    };
    float* degc    = alloc((size_t)N * 4);
    float* dinv    = alloc((size_t)N * 4);
    float* drecip  = alloc((size_t)N * 4);
    float* mdegc   = alloc((size_t)G * 4);
    float* mdinv   = alloc((size_t)G * 4);
    float* mdrecip = alloc((size_t)G * 4);
    float* A       = alloc((size_t)N * 64 * 4);   // xw
    float* Bb      = alloc((size_t)N * 64 * 4);   // agg / h
    float* mzw     = alloc((size_t)G * 128 * 4);
    float* magg    = alloc((size_t)G * 128 * 4);
    float* z1      = alloc((size_t)G * 128 * 4);
    float* zw3     = alloc((size_t)G * 10 * 4);
    (void)ws_size;

    const int* src = ei;
    const int* dst = ei + E;
    const int* ms  = me;
    const int* md  = me + EM;

    hipMemsetAsync(degc, 0, (size_t)N * 4, stream);
    hipMemsetAsync(mdegc, 0, (size_t)G * 4, stream);

    count_kernel<<<(E + 255) / 256, 256, 0, stream>>>(dst, degc, E);
    count_kernel<<<(EM + 255) / 256, 256, 0, stream>>>(md, mdegc, EM);
    finalize_deg<<<(N + 255) / 256, 256, 0, stream>>>(degc, dinv, drecip, N);
    finalize_deg<<<(G + 255) / 256, 256, 0, stream>>>(mdegc, mdinv, mdrecip, G);

    // Layer 1
    gemm_n64<<<(N + 255) / 256, 256, 0, stream>>>(x, W1, b1, drecip, A, Bb, N, 0);
    {
        long long thr = (long long)E * 16;
        edge_agg<64><<<(int)((thr + 255) / 256), 256, 0, stream>>>(src, dst, dinv, A, Bb, E);
    }
    // Layer 2 (relu fused on load; B read/written per-row by same thread)
    gemm_n64<<<(N + 255) / 256, 256, 0, stream>>>(Bb, W2, b2, drecip, A, Bb, N, 1);
    {
        long long thr = (long long)E * 16;
        edge_agg<64><<<(int)((thr + 255) / 256), 256, 0, stream>>>(src, dst, dinv, A, Bb, E);
    }
    // Pooling (relu fused), writes loc directly into d_out
    pool_kernel<<<G, 128, 0, stream>>>(Bb, batch, FW1, Fb1, loc, N);
    // ic + trailing scalar
    ic_kernel<<<(G + 255) / 256, 256, 0, stream>>>(loc, FW2, Fb2, ic, scalar, G);

    // Macro layer 1
    gemm_g128<<<(2 * G + 255) / 256, 256, 0, stream>>>(loc, MW1, mb1, mdrecip, mzw, magg, G);
    {
        long long thr = (long long)EM * 32;
        edge_agg<128><<<(int)((thr + 255) / 256), 256, 0, stream>>>(ms, md, mdinv, mzw, magg, EM);
    }
    bnrelu_kernel<<<(G * 128 + 255) / 256, 256, 0, stream>>>(magg, g1, be1, m1, v1, z1, G * 128);

    // Macro layer 2 -> glob (in d_out)
    gemm_g128<<<(2 * G + 255) / 256, 256, 0, stream>>>(z1, MW2, mb2, mdrecip, mzw, magg, G);
    {
        long long thr = (long long)EM * 32;
        edge_agg<128><<<(int)((thr + 255) / 256), 256, 0, stream>>>(ms, md, mdinv, mzw, magg, EM);
    }
    bnrelu_kernel<<<(G * 128 + 255) / 256, 256, 0, stream>>>(magg, g2, be2, m2, v2, glob, G * 128);

    // hc = GCN(glob, MW3, mb3)
    gemm_g10<<<(G + 255) / 256, 256, 0, stream>>>(glob, MW3, mb3, mdrecip, zw3, hc, G);
    edge_agg10<<<(EM + 255) / 256, 256, 0, stream>>>(ms, md, mdinv, zw3, hc, EM);
}

// Round 2
// 5592.355 us; speedup vs baseline: 2.7028x; 2.7028x over previous
//
#include <hip/hip_runtime.h>

// ---------------------------------------------------------------------------
// SEAL GNN pipeline, fp32.
//   deg (node + macro) -> dinv/drecip
//   L1: xw1 = x@W1;       B = xw1*drecip + b1;  B += scatter(xw1[src]*norm)
//   L2: xw2 = relu(B)@W2; B = xw2*drecip + b2;  B += scatter(...)
//   pool: loc[g] = mean over sorted-batch segment of (relu(B) @ FW1 + Fb1)
//   ic  = loc @ FW2 + Fb2
//   macro L1/L2: GCN(128->128) + BN + relu ; glob = z2
//   hc  = GCN(glob, MW3, mb3)
//
// R2: replaced spilling thread-per-row GEMMs (acc[64] -> 256 VGPR cap ->
// ~10.9 GB scratch traffic per dispatch) with 64x64-tile / 4x4-per-thread
// register-blocked GEMMs (acc[16], LDS-staged operands).
// ---------------------------------------------------------------------------

__global__ void count_kernel(const int* __restrict__ dst, float* __restrict__ cnt, int E) {
    int e = blockIdx.x * blockDim.x + threadIdx.x;
    if (e < E) atomicAdd(&cnt[dst[e]], 1.0f);
}

__global__ void finalize_deg(const float* __restrict__ cnt, float* __restrict__ dinv,
                             float* __restrict__ drecip, int n) {
    int i = blockIdx.x * blockDim.x + threadIdx.x;
    if (i < n) {
        float c = cnt[i] + 1.0f;          // self-loop included
        dinv[i]   = rsqrtf(c);
        drecip[i] = 1.0f / c;
    }
}

// XW = (relu?(X)) @ W  [N x 64 @ 64 x 64];  AGG = XW*drecip + bias
// Tiled: 64 rows x 64 cols per 256-thread block; 4x4 micro-tile per thread.
// X may alias AGG: each block loads its own 64 rows into LDS (sync) before
// any store to the same rows; no cross-block row overlap.
__global__ __launch_bounds__(256) void gemm_n64(const float* __restrict__ X,
                                                const float* __restrict__ W,
                                                const float* __restrict__ bias,
                                                const float* __restrict__ drecip,
                                                float* __restrict__ XW,
                                                float* __restrict__ AGG, int N, int relu_in) {
    __shared__ float Xs[64][68];   // +4 pad: broadcast reads, 2-way bank alias (free)
    __shared__ float Ws[64][64];
    __shared__ float bs[64];
    const int tid = threadIdx.x;
    const int tc = tid & 15;       // col group (4 cols)
    const int tr = tid >> 4;       // row group (4 rows)
    const int r0 = blockIdx.x * 64;

    for (int i = tid; i < 4096; i += 256) Ws[i >> 6][i & 63] = W[i];
    if (tid < 64) bs[tid] = bias[tid];
#pragma unroll
    for (int p = 0; p < 4; p++) {
        int row = p * 16 + (tid >> 4);
        int col = (tid & 15) * 4;
        float4 v = make_float4(0.f, 0.f, 0.f, 0.f);
        if (r0 + row < N) v = *(const float4*)&X[(size_t)(r0 + row) * 64 + col];
        if (relu_in) {
            v.x = fmaxf(v.x, 0.f); v.y = fmaxf(v.y, 0.f);
            v.z = fmaxf(v.z, 0.f); v.w = fmaxf(v.w, 0.f);
        }
        *(float4*)&Xs[row][col] = v;
    }
    __syncthreads();

    float acc[4][4];
#pragma unroll
    for (int i = 0; i < 4; i++)
#pragma unroll
        for (int j = 0; j < 4; j++) acc[i][j] = 0.f;

#pragma unroll 8
    for (int k = 0; k < 64; k++) {
        float4 wv = *(const float4*)&Ws[k][tc * 4];
        float x0 = Xs[tr * 4 + 0][k];
        float x1 = Xs[tr * 4 + 1][k];
        float x2 = Xs[tr * 4 + 2][k];
        float x3 = Xs[tr * 4 + 3][k];
        acc[0][0] += x0 * wv.x; acc[0][1] += x0 * wv.y; acc[0][2] += x0 * wv.z; acc[0][3] += x0 * wv.w;
        acc[1][0] += x1 * wv.x; acc[1][1] += x1 * wv.y; acc[1][2] += x1 * wv.z; acc[1][3] += x1 * wv.w;
        acc[2][0] += x2 * wv.x; acc[2][1] += x2 * wv.y; acc[2][2] += x2 * wv.z; acc[2][3] += x2 * wv.w;
        acc[3][0] += x3 * wv.x; acc[3][1] += x3 * wv.y; acc[3][2] += x3 * wv.z; acc[3][3] += x3 * wv.w;
    }

#pragma unroll
    for (int i = 0; i < 4; i++) {
        int row = r0 + tr * 4 + i;
        if (row >= N) continue;
        float dr = drecip[row];
        float4 a = make_float4(acc[i][0], acc[i][1], acc[i][2], acc[i][3]);
        *(float4*)&XW[(size_t)row * 64 + tc * 4] = a;
        float4 b;
        b.x = a.x * dr + bs[tc * 4 + 0];
        b.y = a.y * dr + bs[tc * 4 + 1];
        b.z = a.z * dr + bs[tc * 4 + 2];
        b.w = a.w * dr + bs[tc * 4 + 3];
        *(float4*)&AGG[(size_t)row * 64 + tc * 4] = b;
    }
}

// AGG[dst] += XW[src] * dinv[src]*dinv[dst]   (F features, F/4 threads per edge)
template <int F>
__global__ void edge_agg(const int* __restrict__ src, const int* __restrict__ dst,
                         const float* __restrict__ dinv, const float* __restrict__ XW,
                         float* __restrict__ AGG, int E) {
    constexpr int TPE = F / 4;
    int idx = blockIdx.x * blockDim.x + threadIdx.x;
    int e = idx / TPE;
    if (e >= E) return;
    int c = (idx % TPE) * 4;
    int s = src[e], d = dst[e];
    float w = dinv[s] * dinv[d];
    float4 v = *(const float4*)(XW + (size_t)s * F + c);
    float* out = AGG + (size_t)d * F + c;
    atomicAdd(out + 0, v.x * w);
    atomicAdd(out + 1, v.y * w);
    atomicAdd(out + 2, v.z * w);
    atomicAdd(out + 3, v.w * w);
}

// loc[g] = mean over batch-segment of (relu(B) @ FW1 + Fb1). batch sorted -> binary search.
__global__ __launch_bounds__(128) void pool_kernel(const float* __restrict__ B,
                                                   const int* __restrict__ batch,
                                                   const float* __restrict__ FW1,
                                                   const float* __restrict__ Fb1,
                                                   float* __restrict__ loc, int N) {
    int g = blockIdx.x;
    int t = threadIdx.x;
    __shared__ float Ws[64 * 128];
    __shared__ float xs[8][64];
    for (int i = t; i < 64 * 128; i += 128) Ws[i] = FW1[i];
    int lo = 0, hi = N;
    while (lo < hi) { int m = (lo + hi) >> 1; if (batch[m] < g) lo = m + 1; else hi = m; }
    int start = lo;
    hi = N;
    while (lo < hi) { int m = (lo + hi) >> 1; if (batch[m] < g + 1) lo = m + 1; else hi = m; }
    int end = lo;
    __syncthreads();
    float acc = 0.f;
    for (int base = start; base < end; base += 8) {
        int m = min(8, end - base);
        for (int i = t; i < m * 64; i += 128) {
            xs[i >> 6][i & 63] = fmaxf(B[(size_t)(base + (i >> 6)) * 64 + (i & 63)], 0.f);
        }
        __syncthreads();
        for (int r = 0; r < m; r++) {
#pragma unroll
            for (int k = 0; k < 64; k++) acc += xs[r][k] * Ws[k * 128 + t];
        }
        __syncthreads();
    }
    int cnt = end - start;
    acc += (float)cnt * Fb1[t];
    loc[(size_t)g * 128 + t] = acc / fmaxf((float)cnt, 1.f);
}

// ic = loc @ FW2 + Fb2  (G x 128 @ 128 x 10); thread 0 also writes the trailing scalar 0.
__global__ __launch_bounds__(256) void ic_kernel(const float* __restrict__ loc,
                                                 const float* __restrict__ FW2,
                                                 const float* __restrict__ Fb2,
                                                 float* __restrict__ ic,
                                                 float* __restrict__ scalar_out, int G) {
    __shared__ float Ws[1280];
    __shared__ float bs[10];
    for (int i = threadIdx.x; i < 1280; i += 256) Ws[i] = FW2[i];
    if (threadIdx.x < 10) bs[threadIdx.x] = Fb2[threadIdx.x];
    __syncthreads();
    int g = blockIdx.x * 256 + threadIdx.x;
    if (g == 0) scalar_out[0] = 0.f;
    if (g >= G) return;
    float acc[10];
#pragma unroll
    for (int j = 0; j < 10; j++) acc[j] = bs[j];
    const float* xr = loc + (size_t)g * 128;
    for (int k = 0; k < 128; k++) {
        float xv = xr[k];
#pragma unroll
        for (int j = 0; j < 10; j++) acc[j] += xv * Ws[k * 10 + j];
    }
    float* o = ic + (size_t)g * 10;
#pragma unroll
    for (int j = 0; j < 10; j++) o[j] = acc[j];
}

// ZW = X @ W [G x 128 @ 128 x 128]; AGG = ZW*mdrecip + bias.
// Tiled: 64 rows x 64 cols per block (grid.y = 2 col-tiles), K chunked by 64.
__global__ __launch_bounds__(256) void gemm_g128(const float* __restrict__ X,
                                                 const float* __restrict__ W,
                                                 const float* __restrict__ bias,
                                                 const float* __restrict__ mdrecip,
                                                 float* __restrict__ ZW,
                                                 float* __restrict__ AGG, int G) {
    __shared__ float Xs[64][68];
    __shared__ float Ws[64][64];
    __shared__ float bs[64];
    const int tid = threadIdx.x;
    const int tc = tid & 15;
    const int tr = tid >> 4;
    const int r0 = blockIdx.x * 64;
    const int c0 = blockIdx.y * 64;

    if (tid < 64) bs[tid] = bias[c0 + tid];

    float acc[4][4];
#pragma unroll
    for (int i = 0; i < 4; i++)
#pragma unroll
        for (int j = 0; j < 4; j++) acc[i][j] = 0.f;

    for (int kc = 0; kc < 2; kc++) {
        __syncthreads();
        for (int i = tid; i < 4096; i += 256)
            Ws[i >> 6][i & 63] = W[(size_t)(kc * 64 + (i >> 6)) * 128 + c0 + (i & 63)];
#pragma unroll
        for (int p = 0; p < 4; p++) {
            int row = p * 16 + (tid >> 4);
            int col = (tid & 15) * 4;
            float4 v = make_float4(0.f, 0.f, 0.f, 0.f);
            if (r0 + row < G) v = *(const float4*)&X[(size_t)(r0 + row) * 128 + kc * 64 + col];
            *(float4*)&Xs[row][col] = v;
        }
        __syncthreads();
#pragma unroll 8
        for (int k = 0; k < 64; k++) {
            float4 wv = *(const float4*)&Ws[k][tc * 4];
            float x0 = Xs[tr * 4 + 0][k];
            float x1 = Xs[tr * 4 + 1][k];
            float x2 = Xs[tr * 4 + 2][k];
            float x3 = Xs[tr * 4 + 3][k];
            acc[0][0] += x0 * wv.x; acc[0][1] += x0 * wv.y; acc[0][2] += x0 * wv.z; acc[0][3] += x0 * wv.w;
            acc[1][0] += x1 * wv.x; acc[1][1] += x1 * wv.y; acc[1][2] += x1 * wv.z; acc[1][3] += x1 * wv.w;
            acc[2][0] += x2 * wv.x; acc[2][1] += x2 * wv.y; acc[2][2] += x2 * wv.z; acc[2][3] += x2 * wv.w;
            acc[3][0] += x3 * wv.x; acc[3][1] += x3 * wv.y; acc[3][2] += x3 * wv.z; acc[3][3] += x3 * wv.w;
        }
    }

#pragma unroll
    for (int i = 0; i < 4; i++) {
        int row = r0 + tr * 4 + i;
        if (row >= G) continue;
        float dr = mdrecip[row];
        float4 a = make_float4(acc[i][0], acc[i][1], acc[i][2], acc[i][3]);
        *(float4*)&ZW[(size_t)row * 128 + c0 + tc * 4] = a;
        float4 b;
        b.x = a.x * dr + bs[tc * 4 + 0];
        b.y = a.y * dr + bs[tc * 4 + 1];
        b.z = a.z * dr + bs[tc * 4 + 2];
        b.w = a.w * dr + bs[tc * 4 + 3];
        *(float4*)&AGG[(size_t)row * 128 + c0 + tc * 4] = b;
    }
}

// Z = relu(BN(A)) elementwise over G*128
__global__ void bnrelu_kernel(const float* __restrict__ A, const float* __restrict__ gam,
                              const float* __restrict__ bet, const float* __restrict__ mean,
                              const float* __restrict__ var, float* __restrict__ Z, int total) {
    int idx = blockIdx.x * blockDim.x + threadIdx.x;
    if (idx >= total) return;
    int j = idx & 127;
    float v = (A[idx] - mean[j]) * rsqrtf(var[j] + 1e-5f) * gam[j] + bet[j];
    Z[idx] = fmaxf(v, 0.f);
}

// ZW = X @ W [G x 128 @ 128 x 10]; HC = ZW*mdrecip + bias
__global__ __launch_bounds__(256) void gemm_g10(const float* __restrict__ X,
                                                const float* __restrict__ W,
                                                const float* __restrict__ bias,
                                                const float* __restrict__ mdrecip,
                                                float* __restrict__ ZW,
                                                float* __restrict__ HC, int G) {
    __shared__ float Ws[1280];
    __shared__ float bs[10];
    for (int i = threadIdx.x; i < 1280; i += 256) Ws[i] = W[i];
    if (threadIdx.x < 10) bs[threadIdx.x] = bias[threadIdx.x];
    __syncthreads();
    int g = blockIdx.x * 256 + threadIdx.x;
    if (g >= G) return;
    float acc[10];
#pragma unroll
    for (int j = 0; j < 10; j++) acc[j] = 0.f;
    const float4* xr = (const float4*)(X + (size_t)g * 128);
#pragma unroll 4
    for (int k4 = 0; k4 < 32; k4++) {
        float4 v = xr[k4];
        float xv[4] = {v.x, v.y, v.z, v.w};
#pragma unroll
        for (int d = 0; d < 4; d++) {
            float xs = xv[d];
            int k = k4 * 4 + d;
#pragma unroll
            for (int j = 0; j < 10; j++) acc[j] += xs * Ws[k * 10 + j];
        }
    }
    float dr = mdrecip[g];
    float* zw = ZW + (size_t)g * 10;
    float* hc = HC + (size_t)g * 10;
#pragma unroll
    for (int j = 0; j < 10; j++) {
        zw[j] = acc[j];
        hc[j] = acc[j] * dr + bs[j];
    }
}

// HC[md] += ZW[ms] * mdinv[ms]*mdinv[md]  (10 features, 1 thread per edge)
__global__ void edge_agg10(const int* __restrict__ ms, const int* __restrict__ md,
                           const float* __restrict__ mdinv, const float* __restrict__ ZW,
                           float* __restrict__ HC, int EM) {
    int e = blockIdx.x * blockDim.x + threadIdx.x;
    if (e >= EM) return;
    int s = ms[e], d = md[e];
    float w = mdinv[s] * mdinv[d];
    const float* zr = ZW + (size_t)s * 10;
    float* out = HC + (size_t)d * 10;
#pragma unroll
    for (int j = 0; j < 10; j++) atomicAdd(out + j, zr[j] * w);
}

extern "C" void kernel_launch(void* const* d_in, const int* in_sizes, int n_in,
                              void* d_out, int out_size, void* d_ws, size_t ws_size,
                              hipStream_t stream) {
    const float* x    = (const float*)d_in[0];
    const int*   ei   = (const int*)d_in[1];
    const int*   batch= (const int*)d_in[2];
    const int*   me   = (const int*)d_in[3];
    const float* W1   = (const float*)d_in[5];
    const float* b1   = (const float*)d_in[6];
    const float* W2   = (const float*)d_in[7];
    const float* b2   = (const float*)d_in[8];
    const float* FW1  = (const float*)d_in[9];
    const float* Fb1  = (const float*)d_in[10];
    const float* FW2  = (const float*)d_in[11];
    const float* Fb2  = (const float*)d_in[12];
    const float* MW1  = (const float*)d_in[13];
    const float* mb1  = (const float*)d_in[14];
    const float* g1   = (const float*)d_in[15];
    const float* be1  = (const float*)d_in[16];
    const float* m1   = (const float*)d_in[17];
    const float* v1   = (const float*)d_in[18];
    const float* MW2  = (const float*)d_in[19];
    const float* mb2  = (const float*)d_in[20];
    const float* g2   = (const float*)d_in[21];
    const float* be2  = (const float*)d_in[22];
    const float* m2   = (const float*)d_in[23];
    const float* v2   = (const float*)d_in[24];
    const float* MW3  = (const float*)d_in[25];
    const float* mb3  = (const float*)d_in[26];

    const int N  = in_sizes[0] / 64;
    const int E  = in_sizes[1] / 2;
    const int EM = in_sizes[3] / 2;
    const int G  = (out_size - 1) / 276;   // out = G*10 + G*10 + G*128 + G*128 + 1

    float* out    = (float*)d_out;
    float* hc     = out;
    float* ic     = out + (size_t)G * 10;
    float* loc    = out + (size_t)G * 20;
    float* glob   = out + (size_t)G * 20 + (size_t)G * 128;
    float* scalar = out + (size_t)G * 276;

    char*  ws  = (char*)d_ws;
    size_t off = 0;
    auto alloc = [&](size_t bytes) -> float* {
        float* p = (float*)(ws + off);
        off += (bytes + 255) & ~(size_t)255;
        return p;
    };
    float* degc    = alloc((size_t)N * 4);
    float* dinv    = alloc((size_t)N * 4);
    float* drecip  = alloc((size_t)N * 4);
    float* mdegc   = alloc((size_t)G * 4);
    float* mdinv   = alloc((size_t)G * 4);
    float* mdrecip = alloc((size_t)G * 4);
    float* A       = alloc((size_t)N * 64 * 4);   // xw
    float* Bb      = alloc((size_t)N * 64 * 4);   // agg / h
    float* mzw     = alloc((size_t)G * 128 * 4);
    float* magg    = alloc((size_t)G * 128 * 4);
    float* z1      = alloc((size_t)G * 128 * 4);
    float* zw3     = alloc((size_t)G * 10 * 4);
    (void)ws_size;

    const int* src = ei;
    const int* dst = ei + E;
    const int* ms  = me;
    const int* md  = me + EM;

    hipMemsetAsync(degc, 0, (size_t)N * 4, stream);
    hipMemsetAsync(mdegc, 0, (size_t)G * 4, stream);

    count_kernel<<<(E + 255) / 256, 256, 0, stream>>>(dst, degc, E);
    count_kernel<<<(EM + 255) / 256, 256, 0, stream>>>(md, mdegc, EM);
    finalize_deg<<<(N + 255) / 256, 256, 0, stream>>>(degc, dinv, drecip, N);
    finalize_deg<<<(G + 255) / 256, 256, 0, stream>>>(mdegc, mdinv, mdrecip, G);

    const int nblk = (N + 63) / 64;

    // Layer 1
    gemm_n64<<<nblk, 256, 0, stream>>>(x, W1, b1, drecip, A, Bb, N, 0);
    {
        long long thr = (long long)E * 16;
        edge_agg<64><<<(int)((thr + 255) / 256), 256, 0, stream>>>(src, dst, dinv, A, Bb, E);
    }
    // Layer 2 (relu fused on load)
    gemm_n64<<<nblk, 256, 0, stream>>>(Bb, W2, b2, drecip, A, Bb, N, 1);
    {
        long long thr = (long long)E * 16;
        edge_agg<64><<<(int)((thr + 255) / 256), 256, 0, stream>>>(src, dst, dinv, A, Bb, E);
    }
    // Pooling (relu fused), writes loc directly into d_out
    pool_kernel<<<G, 128, 0, stream>>>(Bb, batch, FW1, Fb1, loc, N);
    // ic + trailing scalar
    ic_kernel<<<(G + 255) / 256, 256, 0, stream>>>(loc, FW2, Fb2, ic, scalar, G);

    dim3 mg((G + 63) / 64, 2);

    // Macro layer 1
    gemm_g128<<<mg, 256, 0, stream>>>(loc, MW1, mb1, mdrecip, mzw, magg, G);
    {
        long long thr = (long long)EM * 32;
        edge_agg<128><<<(int)((thr + 255) / 256), 256, 0, stream>>>(ms, md, mdinv, mzw, magg, EM);
    }
    bnrelu_kernel<<<(G * 128 + 255) / 256, 256, 0, stream>>>(magg, g1, be1, m1, v1, z1, G * 128);

    // Macro layer 2 -> glob (in d_out)
    gemm_g128<<<mg, 256, 0, stream>>>(z1, MW2, mb2, mdrecip, mzw, magg, G);
    {
        long long thr = (long long)EM * 32;
        edge_agg<128><<<(int)((thr + 255) / 256), 256, 0, stream>>>(ms, md, mdinv, mzw, magg, EM);
    }
    bnrelu_kernel<<<(G * 128 + 255) / 256, 256, 0, stream>>>(magg, g2, be2, m2, v2, glob, G * 128);

    // hc = GCN(glob, MW3, mb3)
    gemm_g10<<<(G + 255) / 256, 256, 0, stream>>>(glob, MW3, mb3, mdrecip, zw3, hc, G);
    edge_agg10<<<(EM + 255) / 256, 256, 0, stream>>>(ms, md, mdinv, zw3, hc, EM);
}

// Round 3
// 1279.010 us; speedup vs baseline: 11.8178x; 4.3724x over previous
//
#include <hip/hip_runtime.h>

// ---------------------------------------------------------------------------
// SEAL GNN pipeline, fp32.
// R3: edge aggregation converted from scatter-atomics (2.5 GB writes, 2.1 ms
// per layer) to gather over a device-built CSR (histogram -> scan -> scatter,
// built once per call, reused by both node layers; macro graph likewise).
// GEMMs now write XW only; self-loop term + bias fused into csr_agg.
// ---------------------------------------------------------------------------

__global__ void hist_kernel(const int* __restrict__ dst, int* __restrict__ hist, int E) {
    int e = blockIdx.x * blockDim.x + threadIdx.x;
    if (e < E) atomicAdd(&hist[dst[e]], 1);
}

__global__ void finalize_deg(const int* __restrict__ hist, float* __restrict__ dinv,
                             float* __restrict__ drecip, int n) {
    int i = blockIdx.x * blockDim.x + threadIdx.x;
    if (i < n) {
        float c = (float)hist[i] + 1.0f;   // self-loop included
        dinv[i]   = rsqrtf(c);
        drecip[i] = 1.0f / c;
    }
}

// Exclusive scan, stage 1: 1024 counts per 256-thread block.
__global__ __launch_bounds__(256) void scan1(const int* __restrict__ cnt, int* __restrict__ pre,
                                             int* __restrict__ bsum, int n) {
    __shared__ int s[256];
    int base = blockIdx.x * 1024;
    int t = threadIdx.x;
    int v[4];
    int loc = 0;
#pragma unroll
    for (int j = 0; j < 4; j++) {
        int i = base + t * 4 + j;
        v[j] = (i < n) ? cnt[i] : 0;
        loc += v[j];
    }
    s[t] = loc;
    __syncthreads();
    for (int off = 1; off < 256; off <<= 1) {
        int x = (t >= off) ? s[t - off] : 0;
        __syncthreads();
        s[t] += x;
        __syncthreads();
    }
    int run = s[t] - loc;     // exclusive prefix of this thread's chunk
    if (t == 255) bsum[blockIdx.x] = s[255];
#pragma unroll
    for (int j = 0; j < 4; j++) {
        int i = base + t * 4 + j;
        if (i < n) pre[i] = run;
        run += v[j];
    }
}

// Stage 2: exclusive scan of block sums in place (nb <= 512).
__global__ __launch_bounds__(512) void scan2(int* __restrict__ bsum, int nb) {
    __shared__ int s[512];
    int t = threadIdx.x;
    int v = (t < nb) ? bsum[t] : 0;
    s[t] = v;
    __syncthreads();
    for (int off = 1; off < 512; off <<= 1) {
        int x = (t >= off) ? s[t - off] : 0;
        __syncthreads();
        s[t] += x;
        __syncthreads();
    }
    if (t < nb) bsum[t] = s[t] - v;
}

// Stage 3: add block offsets; thread 0 writes rowptr[n] = E.
__global__ void scan3(int* __restrict__ pre, const int* __restrict__ bsum, int n, int E) {
    int i = blockIdx.x * blockDim.x + threadIdx.x;
    if (i < n) pre[i] += bsum[i >> 10];
    if (i == 0) pre[n] = E;
}

__global__ void scatter_kernel(const int* __restrict__ src, const int* __restrict__ dst,
                               const float* __restrict__ dinv, int* __restrict__ cursor,
                               int* __restrict__ col, float* __restrict__ wgt, int E) {
    int e = blockIdx.x * blockDim.x + threadIdx.x;
    if (e >= E) return;
    int s = src[e], d = dst[e];
    int p = atomicAdd(&cursor[d], 1);
    col[p] = s;
    wgt[p] = dinv[s] * dinv[d];
}

// B[node] = XW[node]*drecip[node] + bias + sum_{e in CSR[node]} XW[col[e]]*wgt[e]
template <int F>
__global__ __launch_bounds__(256) void csr_agg(const int* __restrict__ rowptr,
                                               const int* __restrict__ col,
                                               const float* __restrict__ wgt,
                                               const float* __restrict__ XW,
                                               const float* __restrict__ bias,
                                               const float* __restrict__ drecip,
                                               float* __restrict__ B, int N) {
    constexpr int TPN = F / 4;        // threads per node
    constexpr int NPB = 256 / TPN;    // nodes per block
    int node = blockIdx.x * NPB + threadIdx.x / TPN;
    int lane = threadIdx.x % TPN;
    if (node >= N) return;
    int c = lane * 4;
    float4 acc = *(const float4*)&XW[(size_t)node * F + c];
    float dr = drecip[node];
    float4 b4 = *(const float4*)&bias[c];
    acc.x = acc.x * dr + b4.x; acc.y = acc.y * dr + b4.y;
    acc.z = acc.z * dr + b4.z; acc.w = acc.w * dr + b4.w;
    int e0 = rowptr[node], e1 = rowptr[node + 1];
    for (int e = e0; e < e1; e++) {
        int s = col[e];
        float w = wgt[e];
        float4 v = *(const float4*)&XW[(size_t)s * F + c];
        acc.x += v.x * w; acc.y += v.y * w;
        acc.z += v.z * w; acc.w += v.w * w;
    }
    *(float4*)&B[(size_t)node * F + c] = acc;
}

// XW = (relu?(X)) @ W  [N x 64 @ 64 x 64]; 64x64 tile, 4x4 micro-tile.
__global__ __launch_bounds__(256) void gemm_n64(const float* __restrict__ X,
                                                const float* __restrict__ W,
                                                float* __restrict__ XW, int N, int relu_in) {
    __shared__ float Xs[64][68];
    __shared__ float Ws[64][64];
    const int tid = threadIdx.x;
    const int tc = tid & 15;
    const int tr = tid >> 4;
    const int r0 = blockIdx.x * 64;

    for (int i = tid; i < 4096; i += 256) Ws[i >> 6][i & 63] = W[i];
#pragma unroll
    for (int p = 0; p < 4; p++) {
        int row = p * 16 + (tid >> 4);
        int col = (tid & 15) * 4;
        float4 v = make_float4(0.f, 0.f, 0.f, 0.f);
        if (r0 + row < N) v = *(const float4*)&X[(size_t)(r0 + row) * 64 + col];
        if (relu_in) {
            v.x = fmaxf(v.x, 0.f); v.y = fmaxf(v.y, 0.f);
            v.z = fmaxf(v.z, 0.f); v.w = fmaxf(v.w, 0.f);
        }
        *(float4*)&Xs[row][col] = v;
    }
    __syncthreads();

    float acc[4][4];
#pragma unroll
    for (int i = 0; i < 4; i++)
#pragma unroll
        for (int j = 0; j < 4; j++) acc[i][j] = 0.f;

#pragma unroll 8
    for (int k = 0; k < 64; k++) {
        float4 wv = *(const float4*)&Ws[k][tc * 4];
        float x0 = Xs[tr * 4 + 0][k];
        float x1 = Xs[tr * 4 + 1][k];
        float x2 = Xs[tr * 4 + 2][k];
        float x3 = Xs[tr * 4 + 3][k];
        acc[0][0] += x0 * wv.x; acc[0][1] += x0 * wv.y; acc[0][2] += x0 * wv.z; acc[0][3] += x0 * wv.w;
        acc[1][0] += x1 * wv.x; acc[1][1] += x1 * wv.y; acc[1][2] += x1 * wv.z; acc[1][3] += x1 * wv.w;
        acc[2][0] += x2 * wv.x; acc[2][1] += x2 * wv.y; acc[2][2] += x2 * wv.z; acc[2][3] += x2 * wv.w;
        acc[3][0] += x3 * wv.x; acc[3][1] += x3 * wv.y; acc[3][2] += x3 * wv.z; acc[3][3] += x3 * wv.w;
    }

#pragma unroll
    for (int i = 0; i < 4; i++) {
        int row = r0 + tr * 4 + i;
        if (row >= N) continue;
        *(float4*)&XW[(size_t)row * 64 + tc * 4] =
            make_float4(acc[i][0], acc[i][1], acc[i][2], acc[i][3]);
    }
}

// loc[g] = mean over batch-segment of (relu(B) @ FW1 + Fb1). batch sorted -> binary search.
__global__ __launch_bounds__(128) void pool_kernel(const float* __restrict__ B,
                                                   const int* __restrict__ batch,
                                                   const float* __restrict__ FW1,
                                                   const float* __restrict__ Fb1,
                                                   float* __restrict__ loc, int N) {
    int g = blockIdx.x;
    int t = threadIdx.x;
    __shared__ float Ws[64 * 128];
    __shared__ float xs[8][64];
    for (int i = t; i < 64 * 128; i += 128) Ws[i] = FW1[i];
    int lo = 0, hi = N;
    while (lo < hi) { int m = (lo + hi) >> 1; if (batch[m] < g) lo = m + 1; else hi = m; }
    int start = lo;
    hi = N;
    while (lo < hi) { int m = (lo + hi) >> 1; if (batch[m] < g + 1) lo = m + 1; else hi = m; }
    int end = lo;
    __syncthreads();
    float acc = 0.f;
    for (int base = start; base < end; base += 8) {
        int m = min(8, end - base);
        for (int i = t; i < m * 64; i += 128) {
            xs[i >> 6][i & 63] = fmaxf(B[(size_t)(base + (i >> 6)) * 64 + (i & 63)], 0.f);
        }
        __syncthreads();
        for (int r = 0; r < m; r++) {
#pragma unroll
            for (int k = 0; k < 64; k++) acc += xs[r][k] * Ws[k * 128 + t];
        }
        __syncthreads();
    }
    int cnt = end - start;
    acc += (float)cnt * Fb1[t];
    loc[(size_t)g * 128 + t] = acc / fmaxf((float)cnt, 1.f);
}

// ic = loc @ FW2 + Fb2; thread 0 also writes the trailing scalar 0.
__global__ __launch_bounds__(256) void ic_kernel(const float* __restrict__ loc,
                                                 const float* __restrict__ FW2,
                                                 const float* __restrict__ Fb2,
                                                 float* __restrict__ ic,
                                                 float* __restrict__ scalar_out, int G) {
    __shared__ float Ws[1280];
    __shared__ float bs[10];
    for (int i = threadIdx.x; i < 1280; i += 256) Ws[i] = FW2[i];
    if (threadIdx.x < 10) bs[threadIdx.x] = Fb2[threadIdx.x];
    __syncthreads();
    int g = blockIdx.x * 256 + threadIdx.x;
    if (g == 0) scalar_out[0] = 0.f;
    if (g >= G) return;
    float acc[10];
#pragma unroll
    for (int j = 0; j < 10; j++) acc[j] = bs[j];
    const float* xr = loc + (size_t)g * 128;
    for (int k = 0; k < 128; k++) {
        float xv = xr[k];
#pragma unroll
        for (int j = 0; j < 10; j++) acc[j] += xv * Ws[k * 10 + j];
    }
    float* o = ic + (size_t)g * 10;
#pragma unroll
    for (int j = 0; j < 10; j++) o[j] = acc[j];
}

// ZW = X @ W [G x 128 @ 128 x 128]; 64x64 tile per block (grid.y = 2 col tiles).
__global__ __launch_bounds__(256) void gemm_g128(const float* __restrict__ X,
                                                 const float* __restrict__ W,
                                                 float* __restrict__ ZW, int G) {
    __shared__ float Xs[64][68];
    __shared__ float Ws[64][64];
    const int tid = threadIdx.x;
    const int tc = tid & 15;
    const int tr = tid >> 4;
    const int r0 = blockIdx.x * 64;
    const int c0 = blockIdx.y * 64;

    float acc[4][4];
#pragma unroll
    for (int i = 0; i < 4; i++)
#pragma unroll
        for (int j = 0; j < 4; j++) acc[i][j] = 0.f;

    for (int kc = 0; kc < 2; kc++) {
        __syncthreads();
        for (int i = tid; i < 4096; i += 256)
            Ws[i >> 6][i & 63] = W[(size_t)(kc * 64 + (i >> 6)) * 128 + c0 + (i & 63)];
#pragma unroll
        for (int p = 0; p < 4; p++) {
            int row = p * 16 + (tid >> 4);
            int col = (tid & 15) * 4;
            float4 v = make_float4(0.f, 0.f, 0.f, 0.f);
            if (r0 + row < G) v = *(const float4*)&X[(size_t)(r0 + row) * 128 + kc * 64 + col];
            *(float4*)&Xs[row][col] = v;
        }
        __syncthreads();
#pragma unroll 8
        for (int k = 0; k < 64; k++) {
            float4 wv = *(const float4*)&Ws[k][tc * 4];
            float x0 = Xs[tr * 4 + 0][k];
            float x1 = Xs[tr * 4 + 1][k];
            float x2 = Xs[tr * 4 + 2][k];
            float x3 = Xs[tr * 4 + 3][k];
            acc[0][0] += x0 * wv.x; acc[0][1] += x0 * wv.y; acc[0][2] += x0 * wv.z; acc[0][3] += x0 * wv.w;
            acc[1][0] += x1 * wv.x; acc[1][1] += x1 * wv.y; acc[1][2] += x1 * wv.z; acc[1][3] += x1 * wv.w;
            acc[2][0] += x2 * wv.x; acc[2][1] += x2 * wv.y; acc[2][2] += x2 * wv.z; acc[2][3] += x2 * wv.w;
            acc[3][0] += x3 * wv.x; acc[3][1] += x3 * wv.y; acc[3][2] += x3 * wv.z; acc[3][3] += x3 * wv.w;
        }
    }

#pragma unroll
    for (int i = 0; i < 4; i++) {
        int row = r0 + tr * 4 + i;
        if (row >= G) continue;
        *(float4*)&ZW[(size_t)row * 128 + c0 + tc * 4] =
            make_float4(acc[i][0], acc[i][1], acc[i][2], acc[i][3]);
    }
}

// Z = relu(BN(A)) elementwise over G*128
__global__ void bnrelu_kernel(const float* __restrict__ A, const float* __restrict__ gam,
                              const float* __restrict__ bet, const float* __restrict__ mean,
                              const float* __restrict__ var, float* __restrict__ Z, int total) {
    int idx = blockIdx.x * blockDim.x + threadIdx.x;
    if (idx >= total) return;
    int j = idx & 127;
    float v = (A[idx] - mean[j]) * rsqrtf(var[j] + 1e-5f) * gam[j] + bet[j];
    Z[idx] = fmaxf(v, 0.f);
}

// ZW = X @ W [G x 128 @ 128 x 10]; HC = ZW*mdrecip + bias
__global__ __launch_bounds__(256) void gemm_g10(const float* __restrict__ X,
                                                const float* __restrict__ W,
                                                const float* __restrict__ bias,
                                                const float* __restrict__ mdrecip,
                                                float* __restrict__ ZW,
                                                float* __restrict__ HC, int G) {
    __shared__ float Ws[1280];
    __shared__ float bs[10];
    for (int i = threadIdx.x; i < 1280; i += 256) Ws[i] = W[i];
    if (threadIdx.x < 10) bs[threadIdx.x] = bias[threadIdx.x];
    __syncthreads();
    int g = blockIdx.x * 256 + threadIdx.x;
    if (g >= G) return;
    float acc[10];
#pragma unroll
    for (int j = 0; j < 10; j++) acc[j] = 0.f;
    const float4* xr = (const float4*)(X + (size_t)g * 128);
#pragma unroll 4
    for (int k4 = 0; k4 < 32; k4++) {
        float4 v = xr[k4];
        float xv[4] = {v.x, v.y, v.z, v.w};
#pragma unroll
        for (int d = 0; d < 4; d++) {
            float xs = xv[d];
            int k = k4 * 4 + d;
#pragma unroll
            for (int j = 0; j < 10; j++) acc[j] += xs * Ws[k * 10 + j];
        }
    }
    float dr = mdrecip[g];
    float* zw = ZW + (size_t)g * 10;
    float* hc = HC + (size_t)g * 10;
#pragma unroll
    for (int j = 0; j < 10; j++) {
        zw[j] = acc[j];
        hc[j] = acc[j] * dr + bs[j];
    }
}

// HC[md] += ZW[ms] * mdinv[ms]*mdinv[md]  (10 features, tiny)
__global__ void edge_agg10(const int* __restrict__ ms, const int* __restrict__ md,
                           const float* __restrict__ mdinv, const float* __restrict__ ZW,
                           float* __restrict__ HC, int EM) {
    int e = blockIdx.x * blockDim.x + threadIdx.x;
    if (e >= EM) return;
    int s = ms[e], d = md[e];
    float w = mdinv[s] * mdinv[d];
    const float* zr = ZW + (size_t)s * 10;
    float* out = HC + (size_t)d * 10;
#pragma unroll
    for (int j = 0; j < 10; j++) atomicAdd(out + j, zr[j] * w);
}

extern "C" void kernel_launch(void* const* d_in, const int* in_sizes, int n_in,
                              void* d_out, int out_size, void* d_ws, size_t ws_size,
                              hipStream_t stream) {
    const float* x    = (const float*)d_in[0];
    const int*   ei   = (const int*)d_in[1];
    const int*   batch= (const int*)d_in[2];
    const int*   me   = (const int*)d_in[3];
    const float* W1   = (const float*)d_in[5];
    const float* b1   = (const float*)d_in[6];
    const float* W2   = (const float*)d_in[7];
    const float* b2   = (const float*)d_in[8];
    const float* FW1  = (const float*)d_in[9];
    const float* Fb1  = (const float*)d_in[10];
    const float* FW2  = (const float*)d_in[11];
    const float* Fb2  = (const float*)d_in[12];
    const float* MW1  = (const float*)d_in[13];
    const float* mb1  = (const float*)d_in[14];
    const float* g1   = (const float*)d_in[15];
    const float* be1  = (const float*)d_in[16];
    const float* m1   = (const float*)d_in[17];
    const float* v1   = (const float*)d_in[18];
    const float* MW2  = (const float*)d_in[19];
    const float* mb2  = (const float*)d_in[20];
    const float* g2   = (const float*)d_in[21];
    const float* be2  = (const float*)d_in[22];
    const float* m2   = (const float*)d_in[23];
    const float* v2   = (const float*)d_in[24];
    const float* MW3  = (const float*)d_in[25];
    const float* mb3  = (const float*)d_in[26];

    const int N  = in_sizes[0] / 64;
    const int E  = in_sizes[1] / 2;
    const int EM = in_sizes[3] / 2;
    const int G  = (out_size - 1) / 276;

    float* out    = (float*)d_out;
    float* hc     = out;
    float* ic     = out + (size_t)G * 10;
    float* loc    = out + (size_t)G * 20;
    float* glob   = out + (size_t)G * 20 + (size_t)G * 128;
    float* scalar = out + (size_t)G * 276;

    char*  ws  = (char*)d_ws;
    size_t off = 0;
    auto alloc = [&](size_t bytes) -> void* {
        void* p = (void*)(ws + off);
        off += (bytes + 255) & ~(size_t)255;
        return p;
    };
    int*   hist    = (int*)alloc((size_t)(N + 1) * 4);   // becomes rowptr prefix input
    int*   rowptr  = (int*)alloc((size_t)(N + 1) * 4);
    int*   cursor  = (int*)alloc((size_t)N * 4);
    int*   bsum    = (int*)alloc(512 * 4);
    int*   col     = (int*)alloc((size_t)E * 4);
    float* wgt     = (float*)alloc((size_t)E * 4);
    float* dinv    = (float*)alloc((size_t)N * 4);
    float* drecip  = (float*)alloc((size_t)N * 4);
    int*   mhist   = (int*)alloc((size_t)(G + 1) * 4);
    int*   mrowptr = (int*)alloc((size_t)(G + 1) * 4);
    int*   mcursor = (int*)alloc((size_t)G * 4);
    int*   mbsum   = (int*)alloc(512 * 4);
    int*   mcol    = (int*)alloc((size_t)EM * 4);
    float* mwgt    = (float*)alloc((size_t)EM * 4);
    float* mdinv   = (float*)alloc((size_t)G * 4);
    float* mdrecip = (float*)alloc((size_t)G * 4);
    float* A       = (float*)alloc((size_t)N * 64 * 4);   // xw
    float* Bb      = (float*)alloc((size_t)N * 64 * 4);   // agg / h
    float* mzw     = (float*)alloc((size_t)G * 128 * 4);
    float* magg    = (float*)alloc((size_t)G * 128 * 4);
    float* z1      = (float*)alloc((size_t)G * 128 * 4);
    float* zw3     = (float*)alloc((size_t)G * 10 * 4);
    (void)ws_size;

    const int* src = ei;
    const int* dst = ei + E;
    const int* ms  = me;
    const int* md  = me + EM;

    // ---- degrees + CSR build (node graph and macro graph) ----
    hipMemsetAsync(hist, 0, (size_t)(N + 1) * 4, stream);
    hipMemsetAsync(mhist, 0, (size_t)(G + 1) * 4, stream);
    hist_kernel<<<(E + 255) / 256, 256, 0, stream>>>(dst, hist, E);
    hist_kernel<<<(EM + 255) / 256, 256, 0, stream>>>(md, mhist, EM);
    finalize_deg<<<(N + 255) / 256, 256, 0, stream>>>(hist, dinv, drecip, N);
    finalize_deg<<<(G + 255) / 256, 256, 0, stream>>>(mhist, mdinv, mdrecip, G);

    const int nb1 = (N + 1023) / 1024;
    scan1<<<nb1, 256, 0, stream>>>(hist, rowptr, bsum, N);
    scan2<<<1, 512, 0, stream>>>(bsum, nb1);
    scan3<<<(N + 255) / 256, 256, 0, stream>>>(rowptr, bsum, N, E);
    const int nb2 = (G + 1023) / 1024;
    scan1<<<nb2, 256, 0, stream>>>(mhist, mrowptr, mbsum, G);
    scan2<<<1, 512, 0, stream>>>(mbsum, nb2);
    scan3<<<(G + 255) / 256, 256, 0, stream>>>(mrowptr, mbsum, G, EM);

    hipMemcpyAsync(cursor, rowptr, (size_t)N * 4, hipMemcpyDeviceToDevice, stream);
    scatter_kernel<<<(E + 255) / 256, 256, 0, stream>>>(src, dst, dinv, cursor, col, wgt, E);
    hipMemcpyAsync(mcursor, mrowptr, (size_t)G * 4, hipMemcpyDeviceToDevice, stream);
    scatter_kernel<<<(EM + 255) / 256, 256, 0, stream>>>(ms, md, mdinv, mcursor, mcol, mwgt, EM);

    const int nblk = (N + 63) / 64;

    // Layer 1
    gemm_n64<<<nblk, 256, 0, stream>>>(x, W1, A, N, 0);
    csr_agg<64><<<(N * 16 + 255) / 256, 256, 0, stream>>>(rowptr, col, wgt, A, b1, drecip, Bb, N);
    // Layer 2 (relu fused on load)
    gemm_n64<<<nblk, 256, 0, stream>>>(Bb, W2, A, N, 1);
    csr_agg<64><<<(N * 16 + 255) / 256, 256, 0, stream>>>(rowptr, col, wgt, A, b2, drecip, Bb, N);
    // Pooling (relu fused) -> loc in d_out
    pool_kernel<<<G, 128, 0, stream>>>(Bb, batch, FW1, Fb1, loc, N);
    ic_kernel<<<(G + 255) / 256, 256, 0, stream>>>(loc, FW2, Fb2, ic, scalar, G);

    dim3 mg((G + 63) / 64, 2);

    // Macro layer 1
    gemm_g128<<<mg, 256, 0, stream>>>(loc, MW1, mzw, G);
    csr_agg<128><<<(G * 32 + 255) / 256, 256, 0, stream>>>(mrowptr, mcol, mwgt, mzw, mb1, mdrecip, magg, G);
    bnrelu_kernel<<<(G * 128 + 255) / 256, 256, 0, stream>>>(magg, g1, be1, m1, v1, z1, G * 128);

    // Macro layer 2 -> glob (in d_out)
    gemm_g128<<<mg, 256, 0, stream>>>(z1, MW2, mzw, G);
    csr_agg<128><<<(G * 32 + 255) / 256, 256, 0, stream>>>(mrowptr, mcol, mwgt, mzw, mb2, mdrecip, magg, G);
    bnrelu_kernel<<<(G * 128 + 255) / 256, 256, 0, stream>>>(magg, g2, be2, m2, v2, glob, G * 128);

    // hc = GCN(glob, MW3, mb3)
    gemm_g10<<<(G + 255) / 256, 256, 0, stream>>>(glob, MW3, mb3, mdrecip, zw3, hc, G);
    edge_agg10<<<(EM + 255) / 256, 256, 0, stream>>>(ms, md, mdinv, zw3, hc, EM);
}

// Round 4
// 1007.498 us; speedup vs baseline: 15.0026x; 1.2695x over previous
//
#include <hip/hip_runtime.h>

// ---------------------------------------------------------------------------
// SEAL GNN pipeline, fp32.
// R4: pooling GEMM commuted past the segment reduction:
//   segment_sum(relu(B)@FW1 + Fb1) == segment_sum(relu(B))@FW1 + cnt*Fb1
// -> bandwidth-bound segment_mean (N x 64 read) + tiny G x 64 @ 64 x 128 GEMM.
// ReLU fused into csr_agg epilogue (all its consumers want relu'd values).
// ---------------------------------------------------------------------------

__global__ void hist_kernel(const int* __restrict__ dst, int* __restrict__ hist, int E) {
    int e = blockIdx.x * blockDim.x + threadIdx.x;
    if (e < E) atomicAdd(&hist[dst[e]], 1);
}

__global__ void finalize_deg(const int* __restrict__ hist, float* __restrict__ dinv,
                             float* __restrict__ drecip, int n) {
    int i = blockIdx.x * blockDim.x + threadIdx.x;
    if (i < n) {
        float c = (float)hist[i] + 1.0f;   // self-loop included
        dinv[i]   = rsqrtf(c);
        drecip[i] = 1.0f / c;
    }
}

// Exclusive scan, stage 1: 1024 counts per 256-thread block.
__global__ __launch_bounds__(256) void scan1(const int* __restrict__ cnt, int* __restrict__ pre,
                                             int* __restrict__ bsum, int n) {
    __shared__ int s[256];
    int base = blockIdx.x * 1024;
    int t = threadIdx.x;
    int v[4];
    int loc = 0;
#pragma unroll
    for (int j = 0; j < 4; j++) {
        int i = base + t * 4 + j;
        v[j] = (i < n) ? cnt[i] : 0;
        loc += v[j];
    }
    s[t] = loc;
    __syncthreads();
    for (int off = 1; off < 256; off <<= 1) {
        int x = (t >= off) ? s[t - off] : 0;
        __syncthreads();
        s[t] += x;
        __syncthreads();
    }
    int run = s[t] - loc;
    if (t == 255) bsum[blockIdx.x] = s[255];
#pragma unroll
    for (int j = 0; j < 4; j++) {
        int i = base + t * 4 + j;
        if (i < n) pre[i] = run;
        run += v[j];
    }
}

// Stage 2: exclusive scan of block sums in place (nb <= 512).
__global__ __launch_bounds__(512) void scan2(int* __restrict__ bsum, int nb) {
    __shared__ int s[512];
    int t = threadIdx.x;
    int v = (t < nb) ? bsum[t] : 0;
    s[t] = v;
    __syncthreads();
    for (int off = 1; off < 512; off <<= 1) {
        int x = (t >= off) ? s[t - off] : 0;
        __syncthreads();
        s[t] += x;
        __syncthreads();
    }
    if (t < nb) bsum[t] = s[t] - v;
}

// Stage 3: add block offsets; thread 0 writes rowptr[n] = E.
__global__ void scan3(int* __restrict__ pre, const int* __restrict__ bsum, int n, int E) {
    int i = blockIdx.x * blockDim.x + threadIdx.x;
    if (i < n) pre[i] += bsum[i >> 10];
    if (i == 0) pre[n] = E;
}

__global__ void scatter_kernel(const int* __restrict__ src, const int* __restrict__ dst,
                               const float* __restrict__ dinv, int* __restrict__ cursor,
                               int* __restrict__ col, float* __restrict__ wgt, int E) {
    int e = blockIdx.x * blockDim.x + threadIdx.x;
    if (e >= E) return;
    int s = src[e], d = dst[e];
    int p = atomicAdd(&cursor[d], 1);
    col[p] = s;
    wgt[p] = dinv[s] * dinv[d];
}

// B[node] = (relu?)( XW[node]*drecip + bias + sum_{CSR} XW[col]*wgt )
template <int F>
__global__ __launch_bounds__(256) void csr_agg(const int* __restrict__ rowptr,
                                               const int* __restrict__ col,
                                               const float* __restrict__ wgt,
                                               const float* __restrict__ XW,
                                               const float* __restrict__ bias,
                                               const float* __restrict__ drecip,
                                               float* __restrict__ B, int N, int relu) {
    constexpr int TPN = F / 4;
    constexpr int NPB = 256 / TPN;
    int node = blockIdx.x * NPB + threadIdx.x / TPN;
    int lane = threadIdx.x % TPN;
    if (node >= N) return;
    int c = lane * 4;
    float4 acc = *(const float4*)&XW[(size_t)node * F + c];
    float dr = drecip[node];
    float4 b4 = *(const float4*)&bias[c];
    acc.x = acc.x * dr + b4.x; acc.y = acc.y * dr + b4.y;
    acc.z = acc.z * dr + b4.z; acc.w = acc.w * dr + b4.w;
    int e0 = rowptr[node], e1 = rowptr[node + 1];
    for (int e = e0; e < e1; e++) {
        int s = col[e];
        float w = wgt[e];
        float4 v = *(const float4*)&XW[(size_t)s * F + c];
        acc.x += v.x * w; acc.y += v.y * w;
        acc.z += v.z * w; acc.w += v.w * w;
    }
    if (relu) {
        acc.x = fmaxf(acc.x, 0.f); acc.y = fmaxf(acc.y, 0.f);
        acc.z = fmaxf(acc.z, 0.f); acc.w = fmaxf(acc.w, 0.f);
    }
    *(float4*)&B[(size_t)node * F + c] = acc;
}

// XW = X @ W  [N x 64 @ 64 x 64]; 64x64 tile, 4x4 micro-tile.
__global__ __launch_bounds__(256) void gemm_n64(const float* __restrict__ X,
                                                const float* __restrict__ W,
                                                float* __restrict__ XW, int N) {
    __shared__ float Xs[64][68];
    __shared__ float Ws[64][64];
    const int tid = threadIdx.x;
    const int tc = tid & 15;
    const int tr = tid >> 4;
    const int r0 = blockIdx.x * 64;

    for (int i = tid; i < 4096; i += 256) Ws[i >> 6][i & 63] = W[i];
#pragma unroll
    for (int p = 0; p < 4; p++) {
        int row = p * 16 + (tid >> 4);
        int col = (tid & 15) * 4;
        float4 v = make_float4(0.f, 0.f, 0.f, 0.f);
        if (r0 + row < N) v = *(const float4*)&X[(size_t)(r0 + row) * 64 + col];
        *(float4*)&Xs[row][col] = v;
    }
    __syncthreads();

    float acc[4][4];
#pragma unroll
    for (int i = 0; i < 4; i++)
#pragma unroll
        for (int j = 0; j < 4; j++) acc[i][j] = 0.f;

#pragma unroll 8
    for (int k = 0; k < 64; k++) {
        float4 wv = *(const float4*)&Ws[k][tc * 4];
        float x0 = Xs[tr * 4 + 0][k];
        float x1 = Xs[tr * 4 + 1][k];
        float x2 = Xs[tr * 4 + 2][k];
        float x3 = Xs[tr * 4 + 3][k];
        acc[0][0] += x0 * wv.x; acc[0][1] += x0 * wv.y; acc[0][2] += x0 * wv.z; acc[0][3] += x0 * wv.w;
        acc[1][0] += x1 * wv.x; acc[1][1] += x1 * wv.y; acc[1][2] += x1 * wv.z; acc[1][3] += x1 * wv.w;
        acc[2][0] += x2 * wv.x; acc[2][1] += x2 * wv.y; acc[2][2] += x2 * wv.z; acc[2][3] += x2 * wv.w;
        acc[3][0] += x3 * wv.x; acc[3][1] += x3 * wv.y; acc[3][2] += x3 * wv.z; acc[3][3] += x3 * wv.w;
    }

#pragma unroll
    for (int i = 0; i < 4; i++) {
        int row = r0 + tr * 4 + i;
        if (row >= N) continue;
        *(float4*)&XW[(size_t)row * 64 + tc * 4] =
            make_float4(acc[i][0], acc[i][1], acc[i][2], acc[i][3]);
    }
}

// M[g] = mean over batch-segment of B rows (B already relu'd); bscale[g] = cnt>0 ? 1 : 0.
__global__ __launch_bounds__(64) void segment_mean(const float* __restrict__ B,
                                                   const int* __restrict__ batch,
                                                   float* __restrict__ M,
                                                   float* __restrict__ bscale, int N) {
    int g = blockIdx.x;
    int t = threadIdx.x;   // 0..63 = feature column
    int lo = 0, hi = N;
    while (lo < hi) { int m = (lo + hi) >> 1; if (batch[m] < g) lo = m + 1; else hi = m; }
    int start = lo;
    hi = N;
    while (lo < hi) { int m = (lo + hi) >> 1; if (batch[m] < g + 1) lo = m + 1; else hi = m; }
    int end = lo;
    float acc = 0.f;
    int i = start;
    for (; i + 4 <= end; i += 4) {
        acc += B[(size_t)(i + 0) * 64 + t];
        acc += B[(size_t)(i + 1) * 64 + t];
        acc += B[(size_t)(i + 2) * 64 + t];
        acc += B[(size_t)(i + 3) * 64 + t];
    }
    for (; i < end; i++) acc += B[(size_t)i * 64 + t];
    int cnt = end - start;
    float inv = (cnt > 0) ? 1.f / (float)cnt : 0.f;
    M[(size_t)g * 64 + t] = acc * inv;
    if (t == 0) bscale[g] = (cnt > 0) ? 1.f : 0.f;
}

// loc = M @ FW1 + bscale*Fb1   [G x 64 @ 64 x 128]; grid.y = 2 col-tiles.
__global__ __launch_bounds__(256) void loc_gemm(const float* __restrict__ M,
                                                const float* __restrict__ FW1,
                                                const float* __restrict__ Fb1,
                                                const float* __restrict__ bscale,
                                                float* __restrict__ loc, int G) {
    __shared__ float Xs[64][68];
    __shared__ float Ws[64][64];
    __shared__ float bs[64];
    const int tid = threadIdx.x;
    const int tc = tid & 15;
    const int tr = tid >> 4;
    const int r0 = blockIdx.x * 64;
    const int c0 = blockIdx.y * 64;

    for (int i = tid; i < 4096; i += 256)
        Ws[i >> 6][i & 63] = FW1[(size_t)(i >> 6) * 128 + c0 + (i & 63)];
    if (tid < 64) bs[tid] = Fb1[c0 + tid];
#pragma unroll
    for (int p = 0; p < 4; p++) {
        int row = p * 16 + (tid >> 4);
        int col = (tid & 15) * 4;
        float4 v = make_float4(0.f, 0.f, 0.f, 0.f);
        if (r0 + row < G) v = *(const float4*)&M[(size_t)(r0 + row) * 64 + col];
        *(float4*)&Xs[row][col] = v;
    }
    __syncthreads();

    float acc[4][4];
#pragma unroll
    for (int i = 0; i < 4; i++)
#pragma unroll
        for (int j = 0; j < 4; j++) acc[i][j] = 0.f;

#pragma unroll 8
    for (int k = 0; k < 64; k++) {
        float4 wv = *(const float4*)&Ws[k][tc * 4];
        float x0 = Xs[tr * 4 + 0][k];
        float x1 = Xs[tr * 4 + 1][k];
        float x2 = Xs[tr * 4 + 2][k];
        float x3 = Xs[tr * 4 + 3][k];
        acc[0][0] += x0 * wv.x; acc[0][1] += x0 * wv.y; acc[0][2] += x0 * wv.z; acc[0][3] += x0 * wv.w;
        acc[1][0] += x1 * wv.x; acc[1][1] += x1 * wv.y; acc[1][2] += x1 * wv.z; acc[1][3] += x1 * wv.w;
        acc[2][0] += x2 * wv.x; acc[2][1] += x2 * wv.y; acc[2][2] += x2 * wv.z; acc[2][3] += x2 * wv.w;
        acc[3][0] += x3 * wv.x; acc[3][1] += x3 * wv.y; acc[3][2] += x3 * wv.z; acc[3][3] += x3 * wv.w;
    }

#pragma unroll
    for (int i = 0; i < 4; i++) {
        int row = r0 + tr * 4 + i;
        if (row >= G) continue;
        float sc = bscale[row];
        float4 o;
        o.x = acc[i][0] + sc * bs[tc * 4 + 0];
        o.y = acc[i][1] + sc * bs[tc * 4 + 1];
        o.z = acc[i][2] + sc * bs[tc * 4 + 2];
        o.w = acc[i][3] + sc * bs[tc * 4 + 3];
        *(float4*)&loc[(size_t)row * 128 + c0 + tc * 4] = o;
    }
}

// ic = loc @ FW2 + Fb2; thread 0 also writes the trailing scalar 0.
__global__ __launch_bounds__(256) void ic_kernel(const float* __restrict__ loc,
                                                 const float* __restrict__ FW2,
                                                 const float* __restrict__ Fb2,
                                                 float* __restrict__ ic,
                                                 float* __restrict__ scalar_out, int G) {
    __shared__ float Ws[1280];
    __shared__ float bs[10];
    for (int i = threadIdx.x; i < 1280; i += 256) Ws[i] = FW2[i];
    if (threadIdx.x < 10) bs[threadIdx.x] = Fb2[threadIdx.x];
    __syncthreads();
    int g = blockIdx.x * 256 + threadIdx.x;
    if (g == 0) scalar_out[0] = 0.f;
    if (g >= G) return;
    float acc[10];
#pragma unroll
    for (int j = 0; j < 10; j++) acc[j] = bs[j];
    const float* xr = loc + (size_t)g * 128;
    for (int k = 0; k < 128; k++) {
        float xv = xr[k];
#pragma unroll
        for (int j = 0; j < 10; j++) acc[j] += xv * Ws[k * 10 + j];
    }
    float* o = ic + (size_t)g * 10;
#pragma unroll
    for (int j = 0; j < 10; j++) o[j] = acc[j];
}

// ZW = X @ W [G x 128 @ 128 x 128]; 64x64 tile per block (grid.y = 2 col tiles).
__global__ __launch_bounds__(256) void gemm_g128(const float* __restrict__ X,
                                                 const float* __restrict__ W,
                                                 float* __restrict__ ZW, int G) {
    __shared__ float Xs[64][68];
    __shared__ float Ws[64][64];
    const int tid = threadIdx.x;
    const int tc = tid & 15;
    const int tr = tid >> 4;
    const int r0 = blockIdx.x * 64;
    const int c0 = blockIdx.y * 64;

    float acc[4][4];
#pragma unroll
    for (int i = 0; i < 4; i++)
#pragma unroll
        for (int j = 0; j < 4; j++) acc[i][j] = 0.f;

    for (int kc = 0; kc < 2; kc++) {
        __syncthreads();
        for (int i = tid; i < 4096; i += 256)
            Ws[i >> 6][i & 63] = W[(size_t)(kc * 64 + (i >> 6)) * 128 + c0 + (i & 63)];
#pragma unroll
        for (int p = 0; p < 4; p++) {
            int row = p * 16 + (tid >> 4);
            int col = (tid & 15) * 4;
            float4 v = make_float4(0.f, 0.f, 0.f, 0.f);
            if (r0 + row < G) v = *(const float4*)&X[(size_t)(r0 + row) * 128 + kc * 64 + col];
            *(float4*)&Xs[row][col] = v;
        }
        __syncthreads();
#pragma unroll 8
        for (int k = 0; k < 64; k++) {
            float4 wv = *(const float4*)&Ws[k][tc * 4];
            float x0 = Xs[tr * 4 + 0][k];
            float x1 = Xs[tr * 4 + 1][k];
            float x2 = Xs[tr * 4 + 2][k];
            float x3 = Xs[tr * 4 + 3][k];
            acc[0][0] += x0 * wv.x; acc[0][1] += x0 * wv.y; acc[0][2] += x0 * wv.z; acc[0][3] += x0 * wv.w;
            acc[1][0] += x1 * wv.x; acc[1][1] += x1 * wv.y; acc[1][2] += x1 * wv.z; acc[1][3] += x1 * wv.w;
            acc[2][0] += x2 * wv.x; acc[2][1] += x2 * wv.y; acc[2][2] += x2 * wv.z; acc[2][3] += x2 * wv.w;
            acc[3][0] += x3 * wv.x; acc[3][1] += x3 * wv.y; acc[3][2] += x3 * wv.z; acc[3][3] += x3 * wv.w;
        }
    }

#pragma unroll
    for (int i = 0; i < 4; i++) {
        int row = r0 + tr * 4 + i;
        if (row >= G) continue;
        *(float4*)&ZW[(size_t)row * 128 + c0 + tc * 4] =
            make_float4(acc[i][0], acc[i][1], acc[i][2], acc[i][3]);
    }
}

// Z = relu(BN(A)) elementwise over G*128
__global__ void bnrelu_kernel(const float* __restrict__ A, const float* __restrict__ gam,
                              const float* __restrict__ bet, const float* __restrict__ mean,
                              const float* __restrict__ var, float* __restrict__ Z, int total) {
    int idx = blockIdx.x * blockDim.x + threadIdx.x;
    if (idx >= total) return;
    int j = idx & 127;
    float v = (A[idx] - mean[j]) * rsqrtf(var[j] + 1e-5f) * gam[j] + bet[j];
    Z[idx] = fmaxf(v, 0.f);
}

// ZW = X @ W [G x 128 @ 128 x 10]; HC = ZW*mdrecip + bias
__global__ __launch_bounds__(256) void gemm_g10(const float* __restrict__ X,
                                                const float* __restrict__ W,
                                                const float* __restrict__ bias,
                                                const float* __restrict__ mdrecip,
                                                float* __restrict__ ZW,
                                                float* __restrict__ HC, int G) {
    __shared__ float Ws[1280];
    __shared__ float bs[10];
    for (int i = threadIdx.x; i < 1280; i += 256) Ws[i] = W[i];
    if (threadIdx.x < 10) bs[threadIdx.x] = bias[threadIdx.x];
    __syncthreads();
    int g = blockIdx.x * 256 + threadIdx.x;
    if (g >= G) return;
    float acc[10];
#pragma unroll
    for (int j = 0; j < 10; j++) acc[j] = 0.f;
    const float4* xr = (const float4*)(X + (size_t)g * 128);
#pragma unroll 4
    for (int k4 = 0; k4 < 32; k4++) {
        float4 v = xr[k4];
        float xv[4] = {v.x, v.y, v.z, v.w};
#pragma unroll
        for (int d = 0; d < 4; d++) {
            float xs = xv[d];
            int k = k4 * 4 + d;
#pragma unroll
            for (int j = 0; j < 10; j++) acc[j] += xs * Ws[k * 10 + j];
        }
    }
    float dr = mdrecip[g];
    float* zw = ZW + (size_t)g * 10;
    float* hc = HC + (size_t)g * 10;
#pragma unroll
    for (int j = 0; j < 10; j++) {
        zw[j] = acc[j];
        hc[j] = acc[j] * dr + bs[j];
    }
}

// HC[md] += ZW[ms] * mdinv[ms]*mdinv[md]  (10 features, tiny)
__global__ void edge_agg10(const int* __restrict__ ms, const int* __restrict__ md,
                           const float* __restrict__ mdinv, const float* __restrict__ ZW,
                           float* __restrict__ HC, int EM) {
    int e = blockIdx.x * blockDim.x + threadIdx.x;
    if (e >= EM) return;
    int s = ms[e], d = md[e];
    float w = mdinv[s] * mdinv[d];
    const float* zr = ZW + (size_t)s * 10;
    float* out = HC + (size_t)d * 10;
#pragma unroll
    for (int j = 0; j < 10; j++) atomicAdd(out + j, zr[j] * w);
}

extern "C" void kernel_launch(void* const* d_in, const int* in_sizes, int n_in,
                              void* d_out, int out_size, void* d_ws, size_t ws_size,
                              hipStream_t stream) {
    const float* x    = (const float*)d_in[0];
    const int*   ei   = (const int*)d_in[1];
    const int*   batch= (const int*)d_in[2];
    const int*   me   = (const int*)d_in[3];
    const float* W1   = (const float*)d_in[5];
    const float* b1   = (const float*)d_in[6];
    const float* W2   = (const float*)d_in[7];
    const float* b2   = (const float*)d_in[8];
    const float* FW1  = (const float*)d_in[9];
    const float* Fb1  = (const float*)d_in[10];
    const float* FW2  = (const float*)d_in[11];
    const float* Fb2  = (const float*)d_in[12];
    const float* MW1  = (const float*)d_in[13];
    const float* mb1  = (const float*)d_in[14];
    const float* g1   = (const float*)d_in[15];
    const float* be1  = (const float*)d_in[16];
    const float* m1   = (const float*)d_in[17];
    const float* v1   = (const float*)d_in[18];
    const float* MW2  = (const float*)d_in[19];
    const float* mb2  = (const float*)d_in[20];
    const float* g2   = (const float*)d_in[21];
    const float* be2  = (const float*)d_in[22];
    const float* m2   = (const float*)d_in[23];
    const float* v2   = (const float*)d_in[24];
    const float* MW3  = (const float*)d_in[25];
    const float* mb3  = (const float*)d_in[26];

    const int N  = in_sizes[0] / 64;
    const int E  = in_sizes[1] / 2;
    const int EM = in_sizes[3] / 2;
    const int G  = (out_size - 1) / 276;

    float* out    = (float*)d_out;
    float* hc     = out;
    float* ic     = out + (size_t)G * 10;
    float* loc    = out + (size_t)G * 20;
    float* glob   = out + (size_t)G * 20 + (size_t)G * 128;
    float* scalar = out + (size_t)G * 276;

    char*  ws  = (char*)d_ws;
    size_t off = 0;
    auto alloc = [&](size_t bytes) -> void* {
        void* p = (void*)(ws + off);
        off += (bytes + 255) & ~(size_t)255;
        return p;
    };
    int*   hist    = (int*)alloc((size_t)(N + 1) * 4);
    int*   rowptr  = (int*)alloc((size_t)(N + 1) * 4);
    int*   cursor  = (int*)alloc((size_t)N * 4);
    int*   bsum    = (int*)alloc(512 * 4);
    int*   col     = (int*)alloc((size_t)E * 4);
    float* wgt     = (float*)alloc((size_t)E * 4);
    float* dinv    = (float*)alloc((size_t)N * 4);
    float* drecip  = (float*)alloc((size_t)N * 4);
    int*   mhist   = (int*)alloc((size_t)(G + 1) * 4);
    int*   mrowptr = (int*)alloc((size_t)(G + 1) * 4);
    int*   mcursor = (int*)alloc((size_t)G * 4);
    int*   mbsum   = (int*)alloc(512 * 4);
    int*   mcol    = (int*)alloc((size_t)EM * 4);
    float* mwgt    = (float*)alloc((size_t)EM * 4);
    float* mdinv   = (float*)alloc((size_t)G * 4);
    float* mdrecip = (float*)alloc((size_t)G * 4);
    float* A       = (float*)alloc((size_t)N * 64 * 4);   // xw
    float* Bb      = (float*)alloc((size_t)N * 64 * 4);   // agg / h (relu'd)
    float* M       = (float*)alloc((size_t)G * 64 * 4);   // segment means
    float* bscale  = (float*)alloc((size_t)G * 4);
    float* mzw     = (float*)alloc((size_t)G * 128 * 4);
    float* magg    = (float*)alloc((size_t)G * 128 * 4);
    float* z1      = (float*)alloc((size_t)G * 128 * 4);
    float* zw3     = (float*)alloc((size_t)G * 10 * 4);
    (void)ws_size;

    const int* src = ei;
    const int* dst = ei + E;
    const int* ms  = me;
    const int* md  = me + EM;

    // ---- degrees + CSR build (node graph and macro graph) ----
    hipMemsetAsync(hist, 0, (size_t)(N + 1) * 4, stream);
    hipMemsetAsync(mhist, 0, (size_t)(G + 1) * 4, stream);
    hist_kernel<<<(E + 255) / 256, 256, 0, stream>>>(dst, hist, E);
    hist_kernel<<<(EM + 255) / 256, 256, 0, stream>>>(md, mhist, EM);
    finalize_deg<<<(N + 255) / 256, 256, 0, stream>>>(hist, dinv, drecip, N);
    finalize_deg<<<(G + 255) / 256, 256, 0, stream>>>(mhist, mdinv, mdrecip, G);

    const int nb1 = (N + 1023) / 1024;
    scan1<<<nb1, 256, 0, stream>>>(hist, rowptr, bsum, N);
    scan2<<<1, 512, 0, stream>>>(bsum, nb1);
    scan3<<<(N + 255) / 256, 256, 0, stream>>>(rowptr, bsum, N, E);
    const int nb2 = (G + 1023) / 1024;
    scan1<<<nb2, 256, 0, stream>>>(mhist, mrowptr, mbsum, G);
    scan2<<<1, 512, 0, stream>>>(mbsum, nb2);
    scan3<<<(G + 255) / 256, 256, 0, stream>>>(mrowptr, mbsum, G, EM);

    hipMemcpyAsync(cursor, rowptr, (size_t)N * 4, hipMemcpyDeviceToDevice, stream);
    scatter_kernel<<<(E + 255) / 256, 256, 0, stream>>>(src, dst, dinv, cursor, col, wgt, E);
    hipMemcpyAsync(mcursor, mrowptr, (size_t)G * 4, hipMemcpyDeviceToDevice, stream);
    scatter_kernel<<<(EM + 255) / 256, 256, 0, stream>>>(ms, md, mdinv, mcursor, mcol, mwgt, EM);

    const int nblk = (N + 63) / 64;

    // Layer 1 (csr_agg emits relu(h1))
    gemm_n64<<<nblk, 256, 0, stream>>>(x, W1, A, N);
    csr_agg<64><<<(N * 16 + 255) / 256, 256, 0, stream>>>(rowptr, col, wgt, A, b1, drecip, Bb, N, 1);
    // Layer 2 (csr_agg emits relu(h2))
    gemm_n64<<<nblk, 256, 0, stream>>>(Bb, W2, A, N);
    csr_agg<64><<<(N * 16 + 255) / 256, 256, 0, stream>>>(rowptr, col, wgt, A, b2, drecip, Bb, N, 1);

    // Pooling: segment mean (bandwidth-bound) + small GEMM -> loc in d_out
    segment_mean<<<G, 64, 0, stream>>>(Bb, batch, M, bscale, N);
    {
        dim3 lg((G + 63) / 64, 2);
        loc_gemm<<<lg, 256, 0, stream>>>(M, FW1, Fb1, bscale, loc, G);
    }
    ic_kernel<<<(G + 255) / 256, 256, 0, stream>>>(loc, FW2, Fb2, ic, scalar, G);

    dim3 mg((G + 63) / 64, 2);

    // Macro layer 1
    gemm_g128<<<mg, 256, 0, stream>>>(loc, MW1, mzw, G);
    csr_agg<128><<<(G * 32 + 255) / 256, 256, 0, stream>>>(mrowptr, mcol, mwgt, mzw, mb1, mdrecip, magg, G, 0);
    bnrelu_kernel<<<(G * 128 + 255) / 256, 256, 0, stream>>>(magg, g1, be1, m1, v1, z1, G * 128);

    // Macro layer 2 -> glob (in d_out)
    gemm_g128<<<mg, 256, 0, stream>>>(z1, MW2, mzw, G);
    csr_agg<128><<<(G * 32 + 255) / 256, 256, 0, stream>>>(mrowptr, mcol, mwgt, mzw, mb2, mdrecip, magg, G, 0);
    bnrelu_kernel<<<(G * 128 + 255) / 256, 256, 0, stream>>>(magg, g2, be2, m2, v2, glob, G * 128);

    // hc = GCN(glob, MW3, mb3)
    gemm_g10<<<(G + 255) / 256, 256, 0, stream>>>(glob, MW3, mb3, mdrecip, zw3, hc, G);
    edge_agg10<<<(EM + 255) / 256, 256, 0, stream>>>(ms, md, mdinv, zw3, hc, EM);
}

// Round 5
// 978.800 us; speedup vs baseline: 15.4424x; 1.0293x over previous
//
#include <hip/hip_runtime.h>

// ---------------------------------------------------------------------------
// SEAL GNN pipeline, fp32.
// R5: wgt[] array eliminated via algebra:
//   sum_e XW[s]*dinv[s]*dinv[d] = dinv[d] * sum_e (XW[s]*dinv[s]),
//   self term XW[d]/deg = (XW[d]*dinv[d])*dinv[d]
// -> GEMMs write A_s = XW*dinv[row]; csr_agg = dinv[d]*(A_s[d]+sum A_s[col])+b.
// Scatter now writes a single 4B col per edge (half the scattered traffic,
// no dinv gathers). csr_agg gather loop unrolled 4-wide for MLP.
// ---------------------------------------------------------------------------

__global__ void hist_kernel(const int* __restrict__ dst, int* __restrict__ hist, int E) {
    int e = blockIdx.x * blockDim.x + threadIdx.x;
    if (e < E) atomicAdd(&hist[dst[e]], 1);
}

__global__ void finalize_deg(const int* __restrict__ hist, float* __restrict__ dinv,
                             float* __restrict__ drecip, int n) {
    int i = blockIdx.x * blockDim.x + threadIdx.x;
    if (i < n) {
        float c = (float)hist[i] + 1.0f;   // self-loop included
        dinv[i]   = rsqrtf(c);
        drecip[i] = 1.0f / c;
    }
}

// Exclusive scan, stage 1: 1024 counts per 256-thread block.
__global__ __launch_bounds__(256) void scan1(const int* __restrict__ cnt, int* __restrict__ pre,
                                             int* __restrict__ bsum, int n) {
    __shared__ int s[256];
    int base = blockIdx.x * 1024;
    int t = threadIdx.x;
    int v[4];
    int loc = 0;
#pragma unroll
    for (int j = 0; j < 4; j++) {
        int i = base + t * 4 + j;
        v[j] = (i < n) ? cnt[i] : 0;
        loc += v[j];
    }
    s[t] = loc;
    __syncthreads();
    for (int off = 1; off < 256; off <<= 1) {
        int x = (t >= off) ? s[t - off] : 0;
        __syncthreads();
        s[t] += x;
        __syncthreads();
    }
    int run = s[t] - loc;
    if (t == 255) bsum[blockIdx.x] = s[255];
#pragma unroll
    for (int j = 0; j < 4; j++) {
        int i = base + t * 4 + j;
        if (i < n) pre[i] = run;
        run += v[j];
    }
}

// Stage 2: exclusive scan of block sums in place (nb <= 512).
__global__ __launch_bounds__(512) void scan2(int* __restrict__ bsum, int nb) {
    __shared__ int s[512];
    int t = threadIdx.x;
    int v = (t < nb) ? bsum[t] : 0;
    s[t] = v;
    __syncthreads();
    for (int off = 1; off < 512; off <<= 1) {
        int x = (t >= off) ? s[t - off] : 0;
        __syncthreads();
        s[t] += x;
        __syncthreads();
    }
    if (t < nb) bsum[t] = s[t] - v;
}

// Stage 3: add block offsets; thread 0 writes rowptr[n] = E.
__global__ void scan3(int* __restrict__ pre, const int* __restrict__ bsum, int n, int E) {
    int i = blockIdx.x * blockDim.x + threadIdx.x;
    if (i < n) pre[i] += bsum[i >> 10];
    if (i == 0) pre[n] = E;
}

__global__ void scatter_kernel(const int* __restrict__ src, const int* __restrict__ dst,
                               int* __restrict__ cursor, int* __restrict__ col, int E) {
    int e = blockIdx.x * blockDim.x + threadIdx.x;
    if (e >= E) return;
    int s = src[e], d = dst[e];
    int p = atomicAdd(&cursor[d], 1);
    col[p] = s;
}

// B[node] = (relu?)( dinv[node]*(A[node] + sum_{CSR} A[col]) + bias )
// A rows are pre-scaled by dinv[row] in the producing GEMM.
template <int F>
__global__ __launch_bounds__(256) void csr_agg(const int* __restrict__ rowptr,
                                               const int* __restrict__ col,
                                               const float* __restrict__ A,
                                               const float* __restrict__ bias,
                                               const float* __restrict__ dinv,
                                               float* __restrict__ B, int N, int relu) {
    constexpr int TPN = F / 4;
    constexpr int NPB = 256 / TPN;
    int node = blockIdx.x * NPB + threadIdx.x / TPN;
    int lane = threadIdx.x % TPN;
    if (node >= N) return;
    int c = lane * 4;
    float4 acc = *(const float4*)&A[(size_t)node * F + c];
    int e0 = rowptr[node], e1 = rowptr[node + 1];
    int e = e0;
    for (; e + 4 <= e1; e += 4) {
        int s0 = col[e + 0], s1 = col[e + 1], s2 = col[e + 2], s3 = col[e + 3];
        float4 v0 = *(const float4*)&A[(size_t)s0 * F + c];
        float4 v1 = *(const float4*)&A[(size_t)s1 * F + c];
        float4 v2 = *(const float4*)&A[(size_t)s2 * F + c];
        float4 v3 = *(const float4*)&A[(size_t)s3 * F + c];
        acc.x += v0.x + v1.x + v2.x + v3.x;
        acc.y += v0.y + v1.y + v2.y + v3.y;
        acc.z += v0.z + v1.z + v2.z + v3.z;
        acc.w += v0.w + v1.w + v2.w + v3.w;
    }
    for (; e < e1; e++) {
        int s = col[e];
        float4 v = *(const float4*)&A[(size_t)s * F + c];
        acc.x += v.x; acc.y += v.y; acc.z += v.z; acc.w += v.w;
    }
    float dv = dinv[node];
    float4 b4 = *(const float4*)&bias[c];
    acc.x = acc.x * dv + b4.x; acc.y = acc.y * dv + b4.y;
    acc.z = acc.z * dv + b4.z; acc.w = acc.w * dv + b4.w;
    if (relu) {
        acc.x = fmaxf(acc.x, 0.f); acc.y = fmaxf(acc.y, 0.f);
        acc.z = fmaxf(acc.z, 0.f); acc.w = fmaxf(acc.w, 0.f);
    }
    *(float4*)&B[(size_t)node * F + c] = acc;
}

// XW = (X @ W) * dinv[row]  [N x 64 @ 64 x 64]; 64x64 tile, 4x4 micro-tile.
__global__ __launch_bounds__(256) void gemm_n64(const float* __restrict__ X,
                                                const float* __restrict__ W,
                                                const float* __restrict__ dinv,
                                                float* __restrict__ XW, int N) {
    __shared__ float Xs[64][68];
    __shared__ float Ws[64][64];
    const int tid = threadIdx.x;
    const int tc = tid & 15;
    const int tr = tid >> 4;
    const int r0 = blockIdx.x * 64;

    for (int i = tid; i < 4096; i += 256) Ws[i >> 6][i & 63] = W[i];
#pragma unroll
    for (int p = 0; p < 4; p++) {
        int row = p * 16 + (tid >> 4);
        int col = (tid & 15) * 4;
        float4 v = make_float4(0.f, 0.f, 0.f, 0.f);
        if (r0 + row < N) v = *(const float4*)&X[(size_t)(r0 + row) * 64 + col];
        *(float4*)&Xs[row][col] = v;
    }
    __syncthreads();

    float acc[4][4];
#pragma unroll
    for (int i = 0; i < 4; i++)
#pragma unroll
        for (int j = 0; j < 4; j++) acc[i][j] = 0.f;

#pragma unroll 8
    for (int k = 0; k < 64; k++) {
        float4 wv = *(const float4*)&Ws[k][tc * 4];
        float x0 = Xs[tr * 4 + 0][k];
        float x1 = Xs[tr * 4 + 1][k];
        float x2 = Xs[tr * 4 + 2][k];
        float x3 = Xs[tr * 4 + 3][k];
        acc[0][0] += x0 * wv.x; acc[0][1] += x0 * wv.y; acc[0][2] += x0 * wv.z; acc[0][3] += x0 * wv.w;
        acc[1][0] += x1 * wv.x; acc[1][1] += x1 * wv.y; acc[1][2] += x1 * wv.z; acc[1][3] += x1 * wv.w;
        acc[2][0] += x2 * wv.x; acc[2][1] += x2 * wv.y; acc[2][2] += x2 * wv.z; acc[2][3] += x2 * wv.w;
        acc[3][0] += x3 * wv.x; acc[3][1] += x3 * wv.y; acc[3][2] += x3 * wv.z; acc[3][3] += x3 * wv.w;
    }

#pragma unroll
    for (int i = 0; i < 4; i++) {
        int row = r0 + tr * 4 + i;
        if (row >= N) continue;
        float dv = dinv[row];
        *(float4*)&XW[(size_t)row * 64 + tc * 4] =
            make_float4(acc[i][0] * dv, acc[i][1] * dv, acc[i][2] * dv, acc[i][3] * dv);
    }
}

// M[g] = mean over batch-segment of B rows (B already relu'd); bscale[g] = cnt>0 ? 1 : 0.
__global__ __launch_bounds__(64) void segment_mean(const float* __restrict__ B,
                                                   const int* __restrict__ batch,
                                                   float* __restrict__ M,
                                                   float* __restrict__ bscale, int N) {
    int g = blockIdx.x;
    int t = threadIdx.x;
    int lo = 0, hi = N;
    while (lo < hi) { int m = (lo + hi) >> 1; if (batch[m] < g) lo = m + 1; else hi = m; }
    int start = lo;
    hi = N;
    while (lo < hi) { int m = (lo + hi) >> 1; if (batch[m] < g + 1) lo = m + 1; else hi = m; }
    int end = lo;
    float acc = 0.f;
    int i = start;
    for (; i + 4 <= end; i += 4) {
        acc += B[(size_t)(i + 0) * 64 + t];
        acc += B[(size_t)(i + 1) * 64 + t];
        acc += B[(size_t)(i + 2) * 64 + t];
        acc += B[(size_t)(i + 3) * 64 + t];
    }
    for (; i < end; i++) acc += B[(size_t)i * 64 + t];
    int cnt = end - start;
    float inv = (cnt > 0) ? 1.f / (float)cnt : 0.f;
    M[(size_t)g * 64 + t] = acc * inv;
    if (t == 0) bscale[g] = (cnt > 0) ? 1.f : 0.f;
}

// loc = M @ FW1 + bscale*Fb1   [G x 64 @ 64 x 128]; grid.y = 2 col-tiles.
__global__ __launch_bounds__(256) void loc_gemm(const float* __restrict__ M,
                                                const float* __restrict__ FW1,
                                                const float* __restrict__ Fb1,
                                                const float* __restrict__ bscale,
                                                float* __restrict__ loc, int G) {
    __shared__ float Xs[64][68];
    __shared__ float Ws[64][64];
    __shared__ float bs[64];
    const int tid = threadIdx.x;
    const int tc = tid & 15;
    const int tr = tid >> 4;
    const int r0 = blockIdx.x * 64;
    const int c0 = blockIdx.y * 64;

    for (int i = tid; i < 4096; i += 256)
        Ws[i >> 6][i & 63] = FW1[(size_t)(i >> 6) * 128 + c0 + (i & 63)];
    if (tid < 64) bs[tid] = Fb1[c0 + tid];
#pragma unroll
    for (int p = 0; p < 4; p++) {
        int row = p * 16 + (tid >> 4);
        int col = (tid & 15) * 4;
        float4 v = make_float4(0.f, 0.f, 0.f, 0.f);
        if (r0 + row < G) v = *(const float4*)&M[(size_t)(r0 + row) * 64 + col];
        *(float4*)&Xs[row][col] = v;
    }
    __syncthreads();

    float acc[4][4];
#pragma unroll
    for (int i = 0; i < 4; i++)
#pragma unroll
        for (int j = 0; j < 4; j++) acc[i][j] = 0.f;

#pragma unroll 8
    for (int k = 0; k < 64; k++) {
        float4 wv = *(const float4*)&Ws[k][tc * 4];
        float x0 = Xs[tr * 4 + 0][k];
        float x1 = Xs[tr * 4 + 1][k];
        float x2 = Xs[tr * 4 + 2][k];
        float x3 = Xs[tr * 4 + 3][k];
        acc[0][0] += x0 * wv.x; acc[0][1] += x0 * wv.y; acc[0][2] += x0 * wv.z; acc[0][3] += x0 * wv.w;
        acc[1][0] += x1 * wv.x; acc[1][1] += x1 * wv.y; acc[1][2] += x1 * wv.z; acc[1][3] += x1 * wv.w;
        acc[2][0] += x2 * wv.x; acc[2][1] += x2 * wv.y; acc[2][2] += x2 * wv.z; acc[2][3] += x2 * wv.w;
        acc[3][0] += x3 * wv.x; acc[3][1] += x3 * wv.y; acc[3][2] += x3 * wv.z; acc[3][3] += x3 * wv.w;
    }

#pragma unroll
    for (int i = 0; i < 4; i++) {
        int row = r0 + tr * 4 + i;
        if (row >= G) continue;
        float sc = bscale[row];
        float4 o;
        o.x = acc[i][0] + sc * bs[tc * 4 + 0];
        o.y = acc[i][1] + sc * bs[tc * 4 + 1];
        o.z = acc[i][2] + sc * bs[tc * 4 + 2];
        o.w = acc[i][3] + sc * bs[tc * 4 + 3];
        *(float4*)&loc[(size_t)row * 128 + c0 + tc * 4] = o;
    }
}

// ic = loc @ FW2 + Fb2; thread 0 also writes the trailing scalar 0.
__global__ __launch_bounds__(256) void ic_kernel(const float* __restrict__ loc,
                                                 const float* __restrict__ FW2,
                                                 const float* __restrict__ Fb2,
                                                 float* __restrict__ ic,
                                                 float* __restrict__ scalar_out, int G) {
    __shared__ float Ws[1280];
    __shared__ float bs[10];
    for (int i = threadIdx.x; i < 1280; i += 256) Ws[i] = FW2[i];
    if (threadIdx.x < 10) bs[threadIdx.x] = Fb2[threadIdx.x];
    __syncthreads();
    int g = blockIdx.x * 256 + threadIdx.x;
    if (g == 0) scalar_out[0] = 0.f;
    if (g >= G) return;
    float acc[10];
#pragma unroll
    for (int j = 0; j < 10; j++) acc[j] = bs[j];
    const float* xr = loc + (size_t)g * 128;
    for (int k = 0; k < 128; k++) {
        float xv = xr[k];
#pragma unroll
        for (int j = 0; j < 10; j++) acc[j] += xv * Ws[k * 10 + j];
    }
    float* o = ic + (size_t)g * 10;
#pragma unroll
    for (int j = 0; j < 10; j++) o[j] = acc[j];
}

// ZW = (X @ W) * dinv[row]  [G x 128 @ 128 x 128]; 64x64 tile (grid.y = 2 col tiles).
__global__ __launch_bounds__(256) void gemm_g128(const float* __restrict__ X,
                                                 const float* __restrict__ W,
                                                 const float* __restrict__ dinv,
                                                 float* __restrict__ ZW, int G) {
    __shared__ float Xs[64][68];
    __shared__ float Ws[64][64];
    const int tid = threadIdx.x;
    const int tc = tid & 15;
    const int tr = tid >> 4;
    const int r0 = blockIdx.x * 64;
    const int c0 = blockIdx.y * 64;

    float acc[4][4];
#pragma unroll
    for (int i = 0; i < 4; i++)
#pragma unroll
        for (int j = 0; j < 4; j++) acc[i][j] = 0.f;

    for (int kc = 0; kc < 2; kc++) {
        __syncthreads();
        for (int i = tid; i < 4096; i += 256)
            Ws[i >> 6][i & 63] = W[(size_t)(kc * 64 + (i >> 6)) * 128 + c0 + (i & 63)];
#pragma unroll
        for (int p = 0; p < 4; p++) {
            int row = p * 16 + (tid >> 4);
            int col = (tid & 15) * 4;
            float4 v = make_float4(0.f, 0.f, 0.f, 0.f);
            if (r0 + row < G) v = *(const float4*)&X[(size_t)(r0 + row) * 128 + kc * 64 + col];
            *(float4*)&Xs[row][col] = v;
        }
        __syncthreads();
#pragma unroll 8
        for (int k = 0; k < 64; k++) {
            float4 wv = *(const float4*)&Ws[k][tc * 4];
            float x0 = Xs[tr * 4 + 0][k];
            float x1 = Xs[tr * 4 + 1][k];
            float x2 = Xs[tr * 4 + 2][k];
            float x3 = Xs[tr * 4 + 3][k];
            acc[0][0] += x0 * wv.x; acc[0][1] += x0 * wv.y; acc[0][2] += x0 * wv.z; acc[0][3] += x0 * wv.w;
            acc[1][0] += x1 * wv.x; acc[1][1] += x1 * wv.y; acc[1][2] += x1 * wv.z; acc[1][3] += x1 * wv.w;
            acc[2][0] += x2 * wv.x; acc[2][1] += x2 * wv.y; acc[2][2] += x2 * wv.z; acc[2][3] += x2 * wv.w;
            acc[3][0] += x3 * wv.x; acc[3][1] += x3 * wv.y; acc[3][2] += x3 * wv.z; acc[3][3] += x3 * wv.w;
        }
    }

#pragma unroll
    for (int i = 0; i < 4; i++) {
        int row = r0 + tr * 4 + i;
        if (row >= G) continue;
        float dv = dinv[row];
        *(float4*)&ZW[(size_t)row * 128 + c0 + tc * 4] =
            make_float4(acc[i][0] * dv, acc[i][1] * dv, acc[i][2] * dv, acc[i][3] * dv);
    }
}

// Z = relu(BN(A)) elementwise over G*128
__global__ void bnrelu_kernel(const float* __restrict__ A, const float* __restrict__ gam,
                              const float* __restrict__ bet, const float* __restrict__ mean,
                              const float* __restrict__ var, float* __restrict__ Z, int total) {
    int idx = blockIdx.x * blockDim.x + threadIdx.x;
    if (idx >= total) return;
    int j = idx & 127;
    float v = (A[idx] - mean[j]) * rsqrtf(var[j] + 1e-5f) * gam[j] + bet[j];
    Z[idx] = fmaxf(v, 0.f);
}

// ZW = X @ W [G x 128 @ 128 x 10]; HC = ZW*mdrecip + bias
__global__ __launch_bounds__(256) void gemm_g10(const float* __restrict__ X,
                                                const float* __restrict__ W,
                                                const float* __restrict__ bias,
                                                const float* __restrict__ mdrecip,
                                                float* __restrict__ ZW,
                                                float* __restrict__ HC, int G) {
    __shared__ float Ws[1280];
    __shared__ float bs[10];
    for (int i = threadIdx.x; i < 1280; i += 256) Ws[i] = W[i];
    if (threadIdx.x < 10) bs[threadIdx.x] = bias[threadIdx.x];
    __syncthreads();
    int g = blockIdx.x * 256 + threadIdx.x;
    if (g >= G) return;
    float acc[10];
#pragma unroll
    for (int j = 0; j < 10; j++) acc[j] = 0.f;
    const float4* xr = (const float4*)(X + (size_t)g * 128);
#pragma unroll 4
    for (int k4 = 0; k4 < 32; k4++) {
        float4 v = xr[k4];
        float xv[4] = {v.x, v.y, v.z, v.w};
#pragma unroll
        for (int d = 0; d < 4; d++) {
            float xs = xv[d];
            int k = k4 * 4 + d;
#pragma unroll
            for (int j = 0; j < 10; j++) acc[j] += xs * Ws[k * 10 + j];
        }
    }
    float dr = mdrecip[g];
    float* zw = ZW + (size_t)g * 10;
    float* hc = HC + (size_t)g * 10;
#pragma unroll
    for (int j = 0; j < 10; j++) {
        zw[j] = acc[j];
        hc[j] = acc[j] * dr + bs[j];
    }
}

// HC[md] += ZW[ms] * mdinv[ms]*mdinv[md]  (10 features, tiny)
__global__ void edge_agg10(const int* __restrict__ ms, const int* __restrict__ md,
                           const float* __restrict__ mdinv, const float* __restrict__ ZW,
                           float* __restrict__ HC, int EM) {
    int e = blockIdx.x * blockDim.x + threadIdx.x;
    if (e >= EM) return;
    int s = ms[e], d = md[e];
    float w = mdinv[s] * mdinv[d];
    const float* zr = ZW + (size_t)s * 10;
    float* out = HC + (size_t)d * 10;
#pragma unroll
    for (int j = 0; j < 10; j++) atomicAdd(out + j, zr[j] * w);
}

extern "C" void kernel_launch(void* const* d_in, const int* in_sizes, int n_in,
                              void* d_out, int out_size, void* d_ws, size_t ws_size,
                              hipStream_t stream) {
    const float* x    = (const float*)d_in[0];
    const int*   ei   = (const int*)d_in[1];
    const int*   batch= (const int*)d_in[2];
    const int*   me   = (const int*)d_in[3];
    const float* W1   = (const float*)d_in[5];
    const float* b1   = (const float*)d_in[6];
    const float* W2   = (const float*)d_in[7];
    const float* b2   = (const float*)d_in[8];
    const float* FW1  = (const float*)d_in[9];
    const float* Fb1  = (const float*)d_in[10];
    const float* FW2  = (const float*)d_in[11];
    const float* Fb2  = (const float*)d_in[12];
    const float* MW1  = (const float*)d_in[13];
    const float* mb1  = (const float*)d_in[14];
    const float* g1   = (const float*)d_in[15];
    const float* be1  = (const float*)d_in[16];
    const float* m1   = (const float*)d_in[17];
    const float* v1   = (const float*)d_in[18];
    const float* MW2  = (const float*)d_in[19];
    const float* mb2  = (const float*)d_in[20];
    const float* g2   = (const float*)d_in[21];
    const float* be2  = (const float*)d_in[22];
    const float* m2   = (const float*)d_in[23];
    const float* v2   = (const float*)d_in[24];
    const float* MW3  = (const float*)d_in[25];
    const float* mb3  = (const float*)d_in[26];

    const int N  = in_sizes[0] / 64;
    const int E  = in_sizes[1] / 2;
    const int EM = in_sizes[3] / 2;
    const int G  = (out_size - 1) / 276;

    float* out    = (float*)d_out;
    float* hc     = out;
    float* ic     = out + (size_t)G * 10;
    float* loc    = out + (size_t)G * 20;
    float* glob   = out + (size_t)G * 20 + (size_t)G * 128;
    float* scalar = out + (size_t)G * 276;

    char*  ws  = (char*)d_ws;
    size_t off = 0;
    auto alloc = [&](size_t bytes) -> void* {
        void* p = (void*)(ws + off);
        off += (bytes + 255) & ~(size_t)255;
        return p;
    };
    int*   hist    = (int*)alloc((size_t)(N + 1) * 4);
    int*   rowptr  = (int*)alloc((size_t)(N + 1) * 4);
    int*   cursor  = (int*)alloc((size_t)N * 4);
    int*   bsum    = (int*)alloc(512 * 4);
    int*   col     = (int*)alloc((size_t)E * 4);
    float* dinv    = (float*)alloc((size_t)N * 4);
    float* drecip  = (float*)alloc((size_t)N * 4);
    int*   mhist   = (int*)alloc((size_t)(G + 1) * 4);
    int*   mrowptr = (int*)alloc((size_t)(G + 1) * 4);
    int*   mcursor = (int*)alloc((size_t)G * 4);
    int*   mbsum   = (int*)alloc(512 * 4);
    int*   mcol    = (int*)alloc((size_t)EM * 4);
    float* mdinv   = (float*)alloc((size_t)G * 4);
    float* mdrecip = (float*)alloc((size_t)G * 4);
    float* A       = (float*)alloc((size_t)N * 64 * 4);   // xw * dinv
    float* Bb      = (float*)alloc((size_t)N * 64 * 4);   // agg / h (relu'd)
    float* M       = (float*)alloc((size_t)G * 64 * 4);   // segment means
    float* bscale  = (float*)alloc((size_t)G * 4);
    float* mzw     = (float*)alloc((size_t)G * 128 * 4);
    float* magg    = (float*)alloc((size_t)G * 128 * 4);
    float* z1      = (float*)alloc((size_t)G * 128 * 4);
    float* zw3     = (float*)alloc((size_t)G * 10 * 4);
    (void)ws_size;

    const int* src = ei;
    const int* dst = ei + E;
    const int* ms  = me;
    const int* md  = me + EM;

    // ---- degrees + CSR build (node graph and macro graph) ----
    hipMemsetAsync(hist, 0, (size_t)(N + 1) * 4, stream);
    hipMemsetAsync(mhist, 0, (size_t)(G + 1) * 4, stream);
    hist_kernel<<<(E + 255) / 256, 256, 0, stream>>>(dst, hist, E);
    hist_kernel<<<(EM + 255) / 256, 256, 0, stream>>>(md, mhist, EM);
    finalize_deg<<<(N + 255) / 256, 256, 0, stream>>>(hist, dinv, drecip, N);
    finalize_deg<<<(G + 255) / 256, 256, 0, stream>>>(mhist, mdinv, mdrecip, G);

    const int nb1 = (N + 1023) / 1024;
    scan1<<<nb1, 256, 0, stream>>>(hist, rowptr, bsum, N);
    scan2<<<1, 512, 0, stream>>>(bsum, nb1);
    scan3<<<(N + 255) / 256, 256, 0, stream>>>(rowptr, bsum, N, E);
    const int nb2 = (G + 1023) / 1024;
    scan1<<<nb2, 256, 0, stream>>>(mhist, mrowptr, mbsum, G);
    scan2<<<1, 512, 0, stream>>>(mbsum, nb2);
    scan3<<<(G + 255) / 256, 256, 0, stream>>>(mrowptr, mbsum, G, EM);

    hipMemcpyAsync(cursor, rowptr, (size_t)N * 4, hipMemcpyDeviceToDevice, stream);
    scatter_kernel<<<(E + 255) / 256, 256, 0, stream>>>(src, dst, cursor, col, E);
    hipMemcpyAsync(mcursor, mrowptr, (size_t)G * 4, hipMemcpyDeviceToDevice, stream);
    scatter_kernel<<<(EM + 255) / 256, 256, 0, stream>>>(ms, md, mcursor, mcol, EM);

    const int nblk = (N + 63) / 64;

    // Layer 1 (csr_agg emits relu(h1))
    gemm_n64<<<nblk, 256, 0, stream>>>(x, W1, dinv, A, N);
    csr_agg<64><<<(N * 16 + 255) / 256, 256, 0, stream>>>(rowptr, col, A, b1, dinv, Bb, N, 1);
    // Layer 2 (csr_agg emits relu(h2))
    gemm_n64<<<nblk, 256, 0, stream>>>(Bb, W2, dinv, A, N);
    csr_agg<64><<<(N * 16 + 255) / 256, 256, 0, stream>>>(rowptr, col, A, b2, dinv, Bb, N, 1);

    // Pooling: segment mean + small GEMM -> loc in d_out
    segment_mean<<<G, 64, 0, stream>>>(Bb, batch, M, bscale, N);
    {
        dim3 lg((G + 63) / 64, 2);
        loc_gemm<<<lg, 256, 0, stream>>>(M, FW1, Fb1, bscale, loc, G);
    }
    ic_kernel<<<(G + 255) / 256, 256, 0, stream>>>(loc, FW2, Fb2, ic, scalar, G);

    dim3 mg((G + 63) / 64, 2);

    // Macro layer 1
    gemm_g128<<<mg, 256, 0, stream>>>(loc, MW1, mdinv, mzw, G);
    csr_agg<128><<<(G * 32 + 255) / 256, 256, 0, stream>>>(mrowptr, mcol, mzw, mb1, mdinv, magg, G, 0);
    bnrelu_kernel<<<(G * 128 + 255) / 256, 256, 0, stream>>>(magg, g1, be1, m1, v1, z1, G * 128);

    // Macro layer 2 -> glob (in d_out)
    gemm_g128<<<mg, 256, 0, stream>>>(z1, MW2, mdinv, mzw, G);
    csr_agg<128><<<(G * 32 + 255) / 256, 256, 0, stream>>>(mrowptr, mcol, mzw, mb2, mdinv, magg, G, 0);
    bnrelu_kernel<<<(G * 128 + 255) / 256, 256, 0, stream>>>(magg, g2, be2, m2, v2, glob, G * 128);

    // hc = GCN(glob, MW3, mb3)
    gemm_g10<<<(G + 255) / 256, 256, 0, stream>>>(glob, MW3, mb3, mdrecip, zw3, hc, G);
    edge_agg10<<<(EM + 255) / 256, 256, 0, stream>>>(ms, md, mdinv, zw3, hc, EM);
}

// Round 6
// 894.850 us; speedup vs baseline: 16.8912x; 1.0938x over previous
//
#include <hip/hip_runtime.h>

// ---------------------------------------------------------------------------
// SEAL GNN pipeline, fp32.
// R6: scatter write-amplification fix. R5's scatter wrote one 64B HBM line
// per 4B col entry (165 MB for a 10 MB payload) because entries of each line
// were written from random XCDs. Now: nodes partitioned into 8 ranges; block b
// only handles dst in range (b%8) -> with round-robin blockIdx->XCD mapping
// each XCD writes one contiguous ~1.25 MB col region that fits its private
// L2, so lines are fully populated before writeback. Correct regardless of
// the actual XCD mapping. Cursor init fused into scan3 (no d2d memcpy).
// ---------------------------------------------------------------------------

__global__ void hist_kernel(const int* __restrict__ dst, int* __restrict__ hist, int E) {
    int e = blockIdx.x * blockDim.x + threadIdx.x;
    if (e < E) atomicAdd(&hist[dst[e]], 1);
}

__global__ void finalize_deg(const int* __restrict__ hist, float* __restrict__ dinv,
                             float* __restrict__ drecip, int n) {
    int i = blockIdx.x * blockDim.x + threadIdx.x;
    if (i < n) {
        float c = (float)hist[i] + 1.0f;   // self-loop included
        dinv[i]   = rsqrtf(c);
        drecip[i] = 1.0f / c;
    }
}

// Exclusive scan, stage 1: 1024 counts per 256-thread block.
__global__ __launch_bounds__(256) void scan1(const int* __restrict__ cnt, int* __restrict__ pre,
                                             int* __restrict__ bsum, int n) {
    __shared__ int s[256];
    int base = blockIdx.x * 1024;
    int t = threadIdx.x;
    int v[4];
    int loc = 0;
#pragma unroll
    for (int j = 0; j < 4; j++) {
        int i = base + t * 4 + j;
        v[j] = (i < n) ? cnt[i] : 0;
        loc += v[j];
    }
    s[t] = loc;
    __syncthreads();
    for (int off = 1; off < 256; off <<= 1) {
        int x = (t >= off) ? s[t - off] : 0;
        __syncthreads();
        s[t] += x;
        __syncthreads();
    }
    int run = s[t] - loc;
    if (t == 255) bsum[blockIdx.x] = s[255];
#pragma unroll
    for (int j = 0; j < 4; j++) {
        int i = base + t * 4 + j;
        if (i < n) pre[i] = run;
        run += v[j];
    }
}

// Stage 2: exclusive scan of block sums in place (nb <= 512).
__global__ __launch_bounds__(512) void scan2(int* __restrict__ bsum, int nb) {
    __shared__ int s[512];
    int t = threadIdx.x;
    int v = (t < nb) ? bsum[t] : 0;
    s[t] = v;
    __syncthreads();
    for (int off = 1; off < 512; off <<= 1) {
        int x = (t >= off) ? s[t - off] : 0;
        __syncthreads();
        s[t] += x;
        __syncthreads();
    }
    if (t < nb) bsum[t] = s[t] - v;
}

// Stage 3: add block offsets; also initializes cursor; writes rowptr[n] = E.
__global__ void scan3(int* __restrict__ pre, const int* __restrict__ bsum,
                      int* __restrict__ cursor, int n, int E) {
    int i = blockIdx.x * blockDim.x + threadIdx.x;
    if (i < n) {
        int v = pre[i] + bsum[i >> 10];
        pre[i] = v;
        cursor[i] = v;
    }
    if (i == 0) pre[n] = E;
}

// XCD-bucketed scatter: block b covers edge-chunk b>>3 and only scatters
// edges whose dst lies in node-range (b&7). With round-robin block->XCD
// mapping, each XCD's col writes stay in one L2-resident contiguous region.
__global__ __launch_bounds__(256) void scatter_xcd(const int* __restrict__ src,
                                                   const int* __restrict__ dst,
                                                   int* __restrict__ cursor,
                                                   int* __restrict__ col,
                                                   int E, int per_chunk, int npx) {
    int bucket = blockIdx.x & 7;
    int chunk  = blockIdx.x >> 3;
    int lo = bucket * npx;
    int hi = lo + npx;
    int e0 = chunk * per_chunk;
    int e1 = min(e0 + per_chunk, E);
    for (int e = e0 + threadIdx.x; e < e1; e += 256) {
        int d = dst[e];
        if (d < lo || d >= hi) continue;
        int p = atomicAdd(&cursor[d], 1);
        col[p] = src[e];
    }
}

// Simple scatter for the tiny macro graph (col region is L2-resident anyway).
__global__ void scatter_kernel(const int* __restrict__ src, const int* __restrict__ dst,
                               int* __restrict__ cursor, int* __restrict__ col, int E) {
    int e = blockIdx.x * blockDim.x + threadIdx.x;
    if (e >= E) return;
    int p = atomicAdd(&cursor[dst[e]], 1);
    col[p] = src[e];
}

// B[node] = (relu?)( dinv[node]*(A[node] + sum_{CSR} A[col]) + bias )
// A rows are pre-scaled by dinv[row] in the producing GEMM.
template <int F>
__global__ __launch_bounds__(256) void csr_agg(const int* __restrict__ rowptr,
                                               const int* __restrict__ col,
                                               const float* __restrict__ A,
                                               const float* __restrict__ bias,
                                               const float* __restrict__ dinv,
                                               float* __restrict__ B, int N, int relu) {
    constexpr int TPN = F / 4;
    constexpr int NPB = 256 / TPN;
    int node = blockIdx.x * NPB + threadIdx.x / TPN;
    int lane = threadIdx.x % TPN;
    if (node >= N) return;
    int c = lane * 4;
    float4 acc = *(const float4*)&A[(size_t)node * F + c];
    int e0 = rowptr[node], e1 = rowptr[node + 1];
    int e = e0;
    for (; e + 4 <= e1; e += 4) {
        int s0 = col[e + 0], s1 = col[e + 1], s2 = col[e + 2], s3 = col[e + 3];
        float4 v0 = *(const float4*)&A[(size_t)s0 * F + c];
        float4 v1 = *(const float4*)&A[(size_t)s1 * F + c];
        float4 v2 = *(const float4*)&A[(size_t)s2 * F + c];
        float4 v3 = *(const float4*)&A[(size_t)s3 * F + c];
        acc.x += v0.x + v1.x + v2.x + v3.x;
        acc.y += v0.y + v1.y + v2.y + v3.y;
        acc.z += v0.z + v1.z + v2.z + v3.z;
        acc.w += v0.w + v1.w + v2.w + v3.w;
    }
    for (; e < e1; e++) {
        int s = col[e];
        float4 v = *(const float4*)&A[(size_t)s * F + c];
        acc.x += v.x; acc.y += v.y; acc.z += v.z; acc.w += v.w;
    }
    float dv = dinv[node];
    float4 b4 = *(const float4*)&bias[c];
    acc.x = acc.x * dv + b4.x; acc.y = acc.y * dv + b4.y;
    acc.z = acc.z * dv + b4.z; acc.w = acc.w * dv + b4.w;
    if (relu) {
        acc.x = fmaxf(acc.x, 0.f); acc.y = fmaxf(acc.y, 0.f);
        acc.z = fmaxf(acc.z, 0.f); acc.w = fmaxf(acc.w, 0.f);
    }
    *(float4*)&B[(size_t)node * F + c] = acc;
}

// XW = (X @ W) * dinv[row]  [N x 64 @ 64 x 64]; 64x64 tile, 4x4 micro-tile.
__global__ __launch_bounds__(256) void gemm_n64(const float* __restrict__ X,
                                                const float* __restrict__ W,
                                                const float* __restrict__ dinv,
                                                float* __restrict__ XW, int N) {
    __shared__ float Xs[64][68];
    __shared__ float Ws[64][64];
    const int tid = threadIdx.x;
    const int tc = tid & 15;
    const int tr = tid >> 4;
    const int r0 = blockIdx.x * 64;

    for (int i = tid; i < 4096; i += 256) Ws[i >> 6][i & 63] = W[i];
#pragma unroll
    for (int p = 0; p < 4; p++) {
        int row = p * 16 + (tid >> 4);
        int col = (tid & 15) * 4;
        float4 v = make_float4(0.f, 0.f, 0.f, 0.f);
        if (r0 + row < N) v = *(const float4*)&X[(size_t)(r0 + row) * 64 + col];
        *(float4*)&Xs[row][col] = v;
    }
    __syncthreads();

    float acc[4][4];
#pragma unroll
    for (int i = 0; i < 4; i++)
#pragma unroll
        for (int j = 0; j < 4; j++) acc[i][j] = 0.f;

#pragma unroll 8
    for (int k = 0; k < 64; k++) {
        float4 wv = *(const float4*)&Ws[k][tc * 4];
        float x0 = Xs[tr * 4 + 0][k];
        float x1 = Xs[tr * 4 + 1][k];
        float x2 = Xs[tr * 4 + 2][k];
        float x3 = Xs[tr * 4 + 3][k];
        acc[0][0] += x0 * wv.x; acc[0][1] += x0 * wv.y; acc[0][2] += x0 * wv.z; acc[0][3] += x0 * wv.w;
        acc[1][0] += x1 * wv.x; acc[1][1] += x1 * wv.y; acc[1][2] += x1 * wv.z; acc[1][3] += x1 * wv.w;
        acc[2][0] += x2 * wv.x; acc[2][1] += x2 * wv.y; acc[2][2] += x2 * wv.z; acc[2][3] += x2 * wv.w;
        acc[3][0] += x3 * wv.x; acc[3][1] += x3 * wv.y; acc[3][2] += x3 * wv.z; acc[3][3] += x3 * wv.w;
    }

#pragma unroll
    for (int i = 0; i < 4; i++) {
        int row = r0 + tr * 4 + i;
        if (row >= N) continue;
        float dv = dinv[row];
        *(float4*)&XW[(size_t)row * 64 + tc * 4] =
            make_float4(acc[i][0] * dv, acc[i][1] * dv, acc[i][2] * dv, acc[i][3] * dv);
    }
}

// M[g] = mean over batch-segment of B rows (B already relu'd); bscale[g] = cnt>0 ? 1 : 0.
__global__ __launch_bounds__(64) void segment_mean(const float* __restrict__ B,
                                                   const int* __restrict__ batch,
                                                   float* __restrict__ M,
                                                   float* __restrict__ bscale, int N) {
    int g = blockIdx.x;
    int t = threadIdx.x;
    int lo = 0, hi = N;
    while (lo < hi) { int m = (lo + hi) >> 1; if (batch[m] < g) lo = m + 1; else hi = m; }
    int start = lo;
    hi = N;
    while (lo < hi) { int m = (lo + hi) >> 1; if (batch[m] < g + 1) lo = m + 1; else hi = m; }
    int end = lo;
    float acc = 0.f;
    int i = start;
    for (; i + 4 <= end; i += 4) {
        acc += B[(size_t)(i + 0) * 64 + t];
        acc += B[(size_t)(i + 1) * 64 + t];
        acc += B[(size_t)(i + 2) * 64 + t];
        acc += B[(size_t)(i + 3) * 64 + t];
    }
    for (; i < end; i++) acc += B[(size_t)i * 64 + t];
    int cnt = end - start;
    float inv = (cnt > 0) ? 1.f / (float)cnt : 0.f;
    M[(size_t)g * 64 + t] = acc * inv;
    if (t == 0) bscale[g] = (cnt > 0) ? 1.f : 0.f;
}

// loc = M @ FW1 + bscale*Fb1   [G x 64 @ 64 x 128]; grid.y = 2 col-tiles.
__global__ __launch_bounds__(256) void loc_gemm(const float* __restrict__ M,
                                                const float* __restrict__ FW1,
                                                const float* __restrict__ Fb1,
                                                const float* __restrict__ bscale,
                                                float* __restrict__ loc, int G) {
    __shared__ float Xs[64][68];
    __shared__ float Ws[64][64];
    __shared__ float bs[64];
    const int tid = threadIdx.x;
    const int tc = tid & 15;
    const int tr = tid >> 4;
    const int r0 = blockIdx.x * 64;
    const int c0 = blockIdx.y * 64;

    for (int i = tid; i < 4096; i += 256)
        Ws[i >> 6][i & 63] = FW1[(size_t)(i >> 6) * 128 + c0 + (i & 63)];
    if (tid < 64) bs[tid] = Fb1[c0 + tid];
#pragma unroll
    for (int p = 0; p < 4; p++) {
        int row = p * 16 + (tid >> 4);
        int col = (tid & 15) * 4;
        float4 v = make_float4(0.f, 0.f, 0.f, 0.f);
        if (r0 + row < G) v = *(const float4*)&M[(size_t)(r0 + row) * 64 + col];
        *(float4*)&Xs[row][col] = v;
    }
    __syncthreads();

    float acc[4][4];
#pragma unroll
    for (int i = 0; i < 4; i++)
#pragma unroll
        for (int j = 0; j < 4; j++) acc[i][j] = 0.f;

#pragma unroll 8
    for (int k = 0; k < 64; k++) {
        float4 wv = *(const float4*)&Ws[k][tc * 4];
        float x0 = Xs[tr * 4 + 0][k];
        float x1 = Xs[tr * 4 + 1][k];
        float x2 = Xs[tr * 4 + 2][k];
        float x3 = Xs[tr * 4 + 3][k];
        acc[0][0] += x0 * wv.x; acc[0][1] += x0 * wv.y; acc[0][2] += x0 * wv.z; acc[0][3] += x0 * wv.w;
        acc[1][0] += x1 * wv.x; acc[1][1] += x1 * wv.y; acc[1][2] += x1 * wv.z; acc[1][3] += x1 * wv.w;
        acc[2][0] += x2 * wv.x; acc[2][1] += x2 * wv.y; acc[2][2] += x2 * wv.z; acc[2][3] += x2 * wv.w;
        acc[3][0] += x3 * wv.x; acc[3][1] += x3 * wv.y; acc[3][2] += x3 * wv.z; acc[3][3] += x3 * wv.w;
    }

#pragma unroll
    for (int i = 0; i < 4; i++) {
        int row = r0 + tr * 4 + i;
        if (row >= G) continue;
        float sc = bscale[row];
        float4 o;
        o.x = acc[i][0] + sc * bs[tc * 4 + 0];
        o.y = acc[i][1] + sc * bs[tc * 4 + 1];
        o.z = acc[i][2] + sc * bs[tc * 4 + 2];
        o.w = acc[i][3] + sc * bs[tc * 4 + 3];
        *(float4*)&loc[(size_t)row * 128 + c0 + tc * 4] = o;
    }
}

// ic = loc @ FW2 + Fb2; thread 0 also writes the trailing scalar 0.
__global__ __launch_bounds__(256) void ic_kernel(const float* __restrict__ loc,
                                                 const float* __restrict__ FW2,
                                                 const float* __restrict__ Fb2,
                                                 float* __restrict__ ic,
                                                 float* __restrict__ scalar_out, int G) {
    __shared__ float Ws[1280];
    __shared__ float bs[10];
    for (int i = threadIdx.x; i < 1280; i += 256) Ws[i] = FW2[i];
    if (threadIdx.x < 10) bs[threadIdx.x] = Fb2[threadIdx.x];
    __syncthreads();
    int g = blockIdx.x * 256 + threadIdx.x;
    if (g == 0) scalar_out[0] = 0.f;
    if (g >= G) return;
    float acc[10];
#pragma unroll
    for (int j = 0; j < 10; j++) acc[j] = bs[j];
    const float* xr = loc + (size_t)g * 128;
    for (int k = 0; k < 128; k++) {
        float xv = xr[k];
#pragma unroll
        for (int j = 0; j < 10; j++) acc[j] += xv * Ws[k * 10 + j];
    }
    float* o = ic + (size_t)g * 10;
#pragma unroll
    for (int j = 0; j < 10; j++) o[j] = acc[j];
}

// ZW = (X @ W) * dinv[row]  [G x 128 @ 128 x 128]; 64x64 tile (grid.y = 2 col tiles).
__global__ __launch_bounds__(256) void gemm_g128(const float* __restrict__ X,
                                                 const float* __restrict__ W,
                                                 const float* __restrict__ dinv,
                                                 float* __restrict__ ZW, int G) {
    __shared__ float Xs[64][68];
    __shared__ float Ws[64][64];
    const int tid = threadIdx.x;
    const int tc = tid & 15;
    const int tr = tid >> 4;
    const int r0 = blockIdx.x * 64;
    const int c0 = blockIdx.y * 64;

    float acc[4][4];
#pragma unroll
    for (int i = 0; i < 4; i++)
#pragma unroll
        for (int j = 0; j < 4; j++) acc[i][j] = 0.f;

    for (int kc = 0; kc < 2; kc++) {
        __syncthreads();
        for (int i = tid; i < 4096; i += 256)
            Ws[i >> 6][i & 63] = W[(size_t)(kc * 64 + (i >> 6)) * 128 + c0 + (i & 63)];
#pragma unroll
        for (int p = 0; p < 4; p++) {
            int row = p * 16 + (tid >> 4);
            int col = (tid & 15) * 4;
            float4 v = make_float4(0.f, 0.f, 0.f, 0.f);
            if (r0 + row < G) v = *(const float4*)&X[(size_t)(r0 + row) * 128 + kc * 64 + col];
            *(float4*)&Xs[row][col] = v;
        }
        __syncthreads();
#pragma unroll 8
        for (int k = 0; k < 64; k++) {
            float4 wv = *(const float4*)&Ws[k][tc * 4];
            float x0 = Xs[tr * 4 + 0][k];
            float x1 = Xs[tr * 4 + 1][k];
            float x2 = Xs[tr * 4 + 2][k];
            float x3 = Xs[tr * 4 + 3][k];
            acc[0][0] += x0 * wv.x; acc[0][1] += x0 * wv.y; acc[0][2] += x0 * wv.z; acc[0][3] += x0 * wv.w;
            acc[1][0] += x1 * wv.x; acc[1][1] += x1 * wv.y; acc[1][2] += x1 * wv.z; acc[1][3] += x1 * wv.w;
            acc[2][0] += x2 * wv.x; acc[2][1] += x2 * wv.y; acc[2][2] += x2 * wv.z; acc[2][3] += x2 * wv.w;
            acc[3][0] += x3 * wv.x; acc[3][1] += x3 * wv.y; acc[3][2] += x3 * wv.z; acc[3][3] += x3 * wv.w;
        }
    }

#pragma unroll
    for (int i = 0; i < 4; i++) {
        int row = r0 + tr * 4 + i;
        if (row >= G) continue;
        float dv = dinv[row];
        *(float4*)&ZW[(size_t)row * 128 + c0 + tc * 4] =
            make_float4(acc[i][0] * dv, acc[i][1] * dv, acc[i][2] * dv, acc[i][3] * dv);
    }
}

// Z = relu(BN(A)) elementwise over G*128
__global__ void bnrelu_kernel(const float* __restrict__ A, const float* __restrict__ gam,
                              const float* __restrict__ bet, const float* __restrict__ mean,
                              const float* __restrict__ var, float* __restrict__ Z, int total) {
    int idx = blockIdx.x * blockDim.x + threadIdx.x;
    if (idx >= total) return;
    int j = idx & 127;
    float v = (A[idx] - mean[j]) * rsqrtf(var[j] + 1e-5f) * gam[j] + bet[j];
    Z[idx] = fmaxf(v, 0.f);
}

// ZW = X @ W [G x 128 @ 128 x 10]; HC = ZW*mdrecip + bias
__global__ __launch_bounds__(256) void gemm_g10(const float* __restrict__ X,
                                                const float* __restrict__ W,
                                                const float* __restrict__ bias,
                                                const float* __restrict__ mdrecip,
                                                float* __restrict__ ZW,
                                                float* __restrict__ HC, int G) {
    __shared__ float Ws[1280];
    __shared__ float bs[10];
    for (int i = threadIdx.x; i < 1280; i += 256) Ws[i] = W[i];
    if (threadIdx.x < 10) bs[threadIdx.x] = bias[threadIdx.x];
    __syncthreads();
    int g = blockIdx.x * 256 + threadIdx.x;
    if (g >= G) return;
    float acc[10];
#pragma unroll
    for (int j = 0; j < 10; j++) acc[j] = 0.f;
    const float4* xr = (const float4*)(X + (size_t)g * 128);
#pragma unroll 4
    for (int k4 = 0; k4 < 32; k4++) {
        float4 v = xr[k4];
        float xv[4] = {v.x, v.y, v.z, v.w};
#pragma unroll
        for (int d = 0; d < 4; d++) {
            float xs = xv[d];
            int k = k4 * 4 + d;
#pragma unroll
            for (int j = 0; j < 10; j++) acc[j] += xs * Ws[k * 10 + j];
        }
    }
    float dr = mdrecip[g];
    float* zw = ZW + (size_t)g * 10;
    float* hc = HC + (size_t)g * 10;
#pragma unroll
    for (int j = 0; j < 10; j++) {
        zw[j] = acc[j];
        hc[j] = acc[j] * dr + bs[j];
    }
}

// HC[md] += ZW[ms] * mdinv[ms]*mdinv[md]  (10 features, tiny)
__global__ void edge_agg10(const int* __restrict__ ms, const int* __restrict__ md,
                           const float* __restrict__ mdinv, const float* __restrict__ ZW,
                           float* __restrict__ HC, int EM) {
    int e = blockIdx.x * blockDim.x + threadIdx.x;
    if (e >= EM) return;
    int s = ms[e], d = md[e];
    float w = mdinv[s] * mdinv[d];
    const float* zr = ZW + (size_t)s * 10;
    float* out = HC + (size_t)d * 10;
#pragma unroll
    for (int j = 0; j < 10; j++) atomicAdd(out + j, zr[j] * w);
}

extern "C" void kernel_launch(void* const* d_in, const int* in_sizes, int n_in,
                              void* d_out, int out_size, void* d_ws, size_t ws_size,
                              hipStream_t stream) {
    const float* x    = (const float*)d_in[0];
    const int*   ei   = (const int*)d_in[1];
    const int*   batch= (const int*)d_in[2];
    const int*   me   = (const int*)d_in[3];
    const float* W1   = (const float*)d_in[5];
    const float* b1   = (const float*)d_in[6];
    const float* W2   = (const float*)d_in[7];
    const float* b2   = (const float*)d_in[8];
    const float* FW1  = (const float*)d_in[9];
    const float* Fb1  = (const float*)d_in[10];
    const float* FW2  = (const float*)d_in[11];
    const float* Fb2  = (const float*)d_in[12];
    const float* MW1  = (const float*)d_in[13];
    const float* mb1  = (const float*)d_in[14];
    const float* g1   = (const float*)d_in[15];
    const float* be1  = (const float*)d_in[16];
    const float* m1   = (const float*)d_in[17];
    const float* v1   = (const float*)d_in[18];
    const float* MW2  = (const float*)d_in[19];
    const float* mb2  = (const float*)d_in[20];
    const float* g2   = (const float*)d_in[21];
    const float* be2  = (const float*)d_in[22];
    const float* m2   = (const float*)d_in[23];
    const float* v2   = (const float*)d_in[24];
    const float* MW3  = (const float*)d_in[25];
    const float* mb3  = (const float*)d_in[26];

    const int N  = in_sizes[0] / 64;
    const int E  = in_sizes[1] / 2;
    const int EM = in_sizes[3] / 2;
    const int G  = (out_size - 1) / 276;

    float* out    = (float*)d_out;
    float* hc     = out;
    float* ic     = out + (size_t)G * 10;
    float* loc    = out + (size_t)G * 20;
    float* glob   = out + (size_t)G * 20 + (size_t)G * 128;
    float* scalar = out + (size_t)G * 276;

    char*  ws  = (char*)d_ws;
    size_t off = 0;
    auto alloc = [&](size_t bytes) -> void* {
        void* p = (void*)(ws + off);
        off += (bytes + 255) & ~(size_t)255;
        return p;
    };
    int*   hist    = (int*)alloc((size_t)(N + 1) * 4);
    int*   rowptr  = (int*)alloc((size_t)(N + 1) * 4);
    int*   cursor  = (int*)alloc((size_t)N * 4);
    int*   bsum    = (int*)alloc(512 * 4);
    int*   col     = (int*)alloc((size_t)E * 4);
    float* dinv    = (float*)alloc((size_t)N * 4);
    float* drecip  = (float*)alloc((size_t)N * 4);
    int*   mhist   = (int*)alloc((size_t)(G + 1) * 4);
    int*   mrowptr = (int*)alloc((size_t)(G + 1) * 4);
    int*   mcursor = (int*)alloc((size_t)G * 4);
    int*   mbsum   = (int*)alloc(512 * 4);
    int*   mcol    = (int*)alloc((size_t)EM * 4);
    float* mdinv   = (float*)alloc((size_t)G * 4);
    float* mdrecip = (float*)alloc((size_t)G * 4);
    float* A       = (float*)alloc((size_t)N * 64 * 4);   // xw * dinv
    float* Bb      = (float*)alloc((size_t)N * 64 * 4);   // agg / h (relu'd)
    float* M       = (float*)alloc((size_t)G * 64 * 4);   // segment means
    float* bscale  = (float*)alloc((size_t)G * 4);
    float* mzw     = (float*)alloc((size_t)G * 128 * 4);
    float* magg    = (float*)alloc((size_t)G * 128 * 4);
    float* z1      = (float*)alloc((size_t)G * 128 * 4);
    float* zw3     = (float*)alloc((size_t)G * 10 * 4);
    (void)ws_size;

    const int* src = ei;
    const int* dst = ei + E;
    const int* ms  = me;
    const int* md  = me + EM;

    // ---- degrees + CSR build (node graph and macro graph) ----
    hipMemsetAsync(hist, 0, (size_t)(N + 1) * 4, stream);
    hipMemsetAsync(mhist, 0, (size_t)(G + 1) * 4, stream);
    hist_kernel<<<(E + 255) / 256, 256, 0, stream>>>(dst, hist, E);
    hist_kernel<<<(EM + 255) / 256, 256, 0, stream>>>(md, mhist, EM);
    finalize_deg<<<(N + 255) / 256, 256, 0, stream>>>(hist, dinv, drecip, N);
    finalize_deg<<<(G + 255) / 256, 256, 0, stream>>>(mhist, mdinv, mdrecip, G);

    const int nb1 = (N + 1023) / 1024;
    scan1<<<nb1, 256, 0, stream>>>(hist, rowptr, bsum, N);
    scan2<<<1, 512, 0, stream>>>(bsum, nb1);
    scan3<<<(N + 255) / 256, 256, 0, stream>>>(rowptr, bsum, cursor, N, E);
    const int nb2 = (G + 1023) / 1024;
    scan1<<<nb2, 256, 0, stream>>>(mhist, mrowptr, mbsum, G);
    scan2<<<1, 512, 0, stream>>>(mbsum, nb2);
    scan3<<<(G + 255) / 256, 256, 0, stream>>>(mrowptr, mbsum, mcursor, G, EM);

    {
        // XCD-bucketed scatter: 8 buckets x nchunks chunks.
        const int nchunks = 2048;
        const int per_chunk = (E + nchunks - 1) / nchunks;
        const int npx = (N + 7) / 8;
        scatter_xcd<<<nchunks * 8, 256, 0, stream>>>(src, dst, cursor, col, E, per_chunk, npx);
    }
    scatter_kernel<<<(EM + 255) / 256, 256, 0, stream>>>(ms, md, mcursor, mcol, EM);

    const int nblk = (N + 63) / 64;

    // Layer 1 (csr_agg emits relu(h1))
    gemm_n64<<<nblk, 256, 0, stream>>>(x, W1, dinv, A, N);
    csr_agg<64><<<(N * 16 + 255) / 256, 256, 0, stream>>>(rowptr, col, A, b1, dinv, Bb, N, 1);
    // Layer 2 (csr_agg emits relu(h2))
    gemm_n64<<<nblk, 256, 0, stream>>>(Bb, W2, dinv, A, N);
    csr_agg<64><<<(N * 16 + 255) / 256, 256, 0, stream>>>(rowptr, col, A, b2, dinv, Bb, N, 1);

    // Pooling: segment mean + small GEMM -> loc in d_out
    segment_mean<<<G, 64, 0, stream>>>(Bb, batch, M, bscale, N);
    {
        dim3 lg((G + 63) / 64, 2);
        loc_gemm<<<lg, 256, 0, stream>>>(M, FW1, Fb1, bscale, loc, G);
    }
    ic_kernel<<<(G + 255) / 256, 256, 0, stream>>>(loc, FW2, Fb2, ic, scalar, G);

    dim3 mg((G + 63) / 64, 2);

    // Macro layer 1
    gemm_g128<<<mg, 256, 0, stream>>>(loc, MW1, mdinv, mzw, G);
    csr_agg<128><<<(G * 32 + 255) / 256, 256, 0, stream>>>(mrowptr, mcol, mzw, mb1, mdinv, magg, G, 0);
    bnrelu_kernel<<<(G * 128 + 255) / 256, 256, 0, stream>>>(magg, g1, be1, m1, v1, z1, G * 128);

    // Macro layer 2 -> glob (in d_out)
    gemm_g128<<<mg, 256, 0, stream>>>(z1, MW2, mdinv, mzw, G);
    csr_agg<128><<<(G * 32 + 255) / 256, 256, 0, stream>>>(mrowptr, mcol, mzw, mb2, mdinv, magg, G, 0);
    bnrelu_kernel<<<(G * 128 + 255) / 256, 256, 0, stream>>>(magg, g2, be2, m2, v2, glob, G * 128);

    // hc = GCN(glob, MW3, mb3)
    gemm_g10<<<(G + 255) / 256, 256, 0, stream>>>(glob, MW3, mb3, mdrecip, zw3, hc, G);
    edge_agg10<<<(EM + 255) / 256, 256, 0, stream>>>(ms, md, mdinv, zw3, hc, EM);
}